// Round 1
// baseline (9885.314 us; speedup 1.0000x reference)
//
#include <hip/hip_runtime.h>
#include <math.h>

#define DOT4(a,b) ((a).x*(b).x + (a).y*(b).y + (a).z*(b).z + (a).w*(b).w)

// ---------------- K0a: CPB MLP table: (343,3) -> relu(512) -> (343,6) ----------------
__global__ __launch_bounds__(256) void k_cpb_table(
        const float* __restrict__ rtab, const float* __restrict__ w1,
        const float* __restrict__ b1, const float* __restrict__ w2,
        float* __restrict__ table_out) {
    int idx = blockIdx.x * 256 + threadIdx.x;
    if (idx >= 343 * 6) return;
    int r = idx / 6, head = idx - r * 6;
    float t0 = rtab[r*3+0], t1 = rtab[r*3+1], t2 = rtab[r*3+2];
    float s = 0.f;
    for (int j = 0; j < 512; ++j) {
        float a = t0*w1[j*3+0] + t1*w1[j*3+1] + t2*w1[j*3+2] + b1[j];
        a = fmaxf(a, 0.f);
        s += a * w2[head*512 + j];
    }
    table_out[idx] = s;   // layout [r][head]
}

// ---------------- K0b: gather + 16*sigmoid -> bias16[6][64][64] ----------------
__global__ __launch_bounds__(256) void k_bias16(
        const float* __restrict__ table_out, const int* __restrict__ ridx,
        float* __restrict__ bias16) {
    int idx = blockIdx.x * 256 + threadIdx.x;
    if (idx >= 6 * 64 * 64) return;
    int head = idx >> 12;
    int nm = idx & 4095;
    float v = table_out[ridx[nm] * 6 + head];
    bias16[idx] = 16.f / (1.f + expf(-v));
}

// ---------------- K1: LN1 + roll(-2) + window partition -> buf1 [win][c][n] ----------------
__global__ __launch_bounds__(256) void k_ln1(
        const float* __restrict__ x, const float* __restrict__ nw,
        const float* __restrict__ nb, float* __restrict__ buf1) {
    __shared__ float xs[64 * 193];
    __shared__ float muS[64], invS[64];
    const int wb = blockIdx.x;            // 0..1727
    const int b = wb / 216, win = wb - b * 216;
    const int wdi = win / 36, whi = (win / 6) % 6, wwi = win % 6;
    const int t = threadIdx.x;
    const int n = t >> 2, sub = t & 3;    // 4 lanes per token, 48 ch each
    const int id = n >> 4, ih = (n >> 2) & 3, iw = n & 3;
    const int dsrc = (wdi*4 + id + 2) % 24;
    const int hsrc = (whi*4 + ih + 2) % 24;
    const int wsrc = (wwi*4 + iw + 2) % 24;
    const float* xr = x + (size_t)(((b*24 + dsrc)*24 + hsrc)*24 + wsrc) * 192 + sub*48;
    float sum = 0.f, ssum = 0.f;
    #pragma unroll
    for (int j4 = 0; j4 < 12; ++j4) {
        float4 q = reinterpret_cast<const float4*>(xr)[j4];
        sum  += q.x + q.y + q.z + q.w;
        ssum += q.x*q.x + q.y*q.y + q.z*q.z + q.w*q.w;
        int c = sub*48 + j4*4;
        xs[n*193 + c+0] = q.x;
        xs[n*193 + c+1] = q.y;
        xs[n*193 + c+2] = q.z;
        xs[n*193 + c+3] = q.w;
    }
    sum  += __shfl_xor(sum, 1);  sum  += __shfl_xor(sum, 2);
    ssum += __shfl_xor(ssum, 1); ssum += __shfl_xor(ssum, 2);
    if (sub == 0) {
        float mu = sum * (1.f/192.f);
        float var = ssum * (1.f/192.f) - mu*mu;
        muS[n] = mu;
        invS[n] = rsqrtf(var + 1e-5f);
    }
    __syncthreads();
    float* outp = buf1 + (size_t)wb * 12288;
    #pragma unroll
    for (int i = 0; i < 48; ++i) {
        int j2 = i*256 + t;
        int c = j2 >> 6, nn = j2 & 63;
        outp[j2] = (xs[nn*193 + c] - muS[nn]) * invS[nn] * nw[c] + nb[c];
    }
}

// ---------------- K2: per-(window,head) QKV + cosine attn + bias + mask + softmax + PV ----------------
__global__ __launch_bounds__(256) void k_attn(
        const float* __restrict__ buf1, const float* __restrict__ qkvw,
        const float* __restrict__ ls, const float* __restrict__ bias16,
        const float* __restrict__ amask, float* __restrict__ buf2) {
    __shared__ float qs[64 * 36];
    __shared__ float ks[64 * 36];
    __shared__ float vs[64 * 36];
    __shared__ float at[64 * 68];
    const int bid = blockIdx.x;
    const int wb = bid / 6, head = bid - (bid / 6) * 6;
    const int win = wb % 216;
    const int t = threadIdx.x;

    // ---- QKV: 4 tokens x 6 outputs per thread, c-major window reads ----
    {
        const int ng = t & 15, og = t >> 4;
        const float* bw = buf1 + (size_t)wb * 12288 + ng * 4;
        float acc[4][6];
        #pragma unroll
        for (int a = 0; a < 4; ++a)
            #pragma unroll
            for (int i = 0; i < 6; ++i) acc[a][i] = 0.f;
        const float4* wp[6];
        #pragma unroll
        for (int i = 0; i < 6; ++i) {
            int o = og*6 + i;
            int mat = o >> 5, dh = o & 31;
            wp[i] = reinterpret_cast<const float4*>(qkvw + (size_t)(mat*192 + head*32 + dh) * 192);
        }
        for (int c4 = 0; c4 < 48; ++c4) {
            float4 x0 = *reinterpret_cast<const float4*>(bw + (c4*4+0)*64);
            float4 x1 = *reinterpret_cast<const float4*>(bw + (c4*4+1)*64);
            float4 x2 = *reinterpret_cast<const float4*>(bw + (c4*4+2)*64);
            float4 x3 = *reinterpret_cast<const float4*>(bw + (c4*4+3)*64);
            #pragma unroll
            for (int i = 0; i < 6; ++i) {
                float4 w = wp[i][c4];
                acc[0][i] += x0.x*w.x + x1.x*w.y + x2.x*w.z + x3.x*w.w;
                acc[1][i] += x0.y*w.x + x1.y*w.y + x2.y*w.z + x3.y*w.w;
                acc[2][i] += x0.z*w.x + x1.z*w.y + x2.z*w.z + x3.z*w.w;
                acc[3][i] += x0.w*w.x + x1.w*w.y + x2.w*w.z + x3.w*w.w;
            }
        }
        #pragma unroll
        for (int i = 0; i < 6; ++i) {
            int o = og*6 + i;
            int mat = o >> 5, dh = o & 31;
            float* dst = (mat == 0) ? qs : ((mat == 1) ? ks : vs);
            #pragma unroll
            for (int a = 0; a < 4; ++a)
                dst[(ng*4 + a)*36 + dh] = acc[a][i];
        }
    }
    __syncthreads();

    // ---- normalize q (fold logit scale) and k rows ----
    if (t < 128) {
        const int which = t >> 6, r = t & 63;
        float* p = which ? (ks + r*36) : (qs + r*36);
        float ss = 0.f;
        #pragma unroll
        for (int d4 = 0; d4 < 8; ++d4) {
            float4 q = *reinterpret_cast<const float4*>(p + d4*4);
            ss += DOT4(q, q);
        }
        float f = 1.f / fmaxf(sqrtf(ss), 1e-12f);
        if (which == 0) f *= expf(fminf(ls[head], 4.6051701859880914f));
        #pragma unroll
        for (int d4 = 0; d4 < 8; ++d4) {
            float4 q = *reinterpret_cast<const float4*>(p + d4*4);
            q.x *= f; q.y *= f; q.z *= f; q.w *= f;
            *reinterpret_cast<float4*>(p + d4*4) = q;
        }
    }
    __syncthreads();

    // ---- scores: each thread owns column m, 16 rows ----
    {
        const int m = t & 63, nblk = t >> 6;
        float4 kr[8];
        #pragma unroll
        for (int d4 = 0; d4 < 8; ++d4)
            kr[d4] = *reinterpret_cast<const float4*>(ks + m*36 + d4*4);
        const float* bi = bias16 + head*4096 + m;
        const float* mk = amask + (size_t)win*4096 + m;
        #pragma unroll
        for (int i = 0; i < 16; ++i) {
            int n = i*4 + nblk;
            float s = 0.f;
            #pragma unroll
            for (int d4 = 0; d4 < 8; ++d4) {
                float4 q4 = *reinterpret_cast<const float4*>(qs + n*36 + d4*4);
                s += DOT4(q4, kr[d4]);
            }
            at[n*68 + m] = s + bi[n*64] + mk[n*64];
        }
    }
    __syncthreads();

    // ---- softmax per row (4 lanes per row) ----
    {
        const int r = t >> 2, kq = t & 3;
        float* ar = at + r*68 + kq*16;
        float mx = -1e30f;
        #pragma unroll
        for (int j = 0; j < 16; ++j) mx = fmaxf(mx, ar[j]);
        mx = fmaxf(mx, __shfl_xor(mx, 1));
        mx = fmaxf(mx, __shfl_xor(mx, 2));
        float sm = 0.f;
        #pragma unroll
        for (int j = 0; j < 16; ++j) { float e = expf(ar[j] - mx); ar[j] = e; sm += e; }
        sm += __shfl_xor(sm, 1); sm += __shfl_xor(sm, 2);
        float rs = 1.f / sm;
        #pragma unroll
        for (int j = 0; j < 16; ++j) ar[j] *= rs;
    }
    __syncthreads();

    // ---- PV: thread owns (dh, 8 rows) ----
    {
        const int dh = t & 31, nb2 = t >> 5;
        float accO[8] = {0,0,0,0,0,0,0,0};
        for (int m4 = 0; m4 < 16; ++m4) {
            float v0 = vs[(m4*4+0)*36 + dh];
            float v1 = vs[(m4*4+1)*36 + dh];
            float v2 = vs[(m4*4+2)*36 + dh];
            float v3 = vs[(m4*4+3)*36 + dh];
            #pragma unroll
            for (int i = 0; i < 8; ++i) {
                float4 a4 = *reinterpret_cast<const float4*>(at + (i*8 + nb2)*68 + m4*4);
                accO[i] += a4.x*v0 + a4.y*v1 + a4.z*v2 + a4.w*v3;
            }
        }
        float* op = buf2 + (size_t)wb * 12288 + head*32 + dh;
        #pragma unroll
        for (int i = 0; i < 8; ++i)
            op[(i*8 + nb2) * 192] = accO[i];
    }
}

// ---------------- K3: proj + window reverse + roll(+2) + residual -> d_out ----------------
__global__ __launch_bounds__(256) void k_proj(
        const float* __restrict__ buf2, const float* __restrict__ x,
        const float* __restrict__ pw, const float* __restrict__ pb,
        float* __restrict__ out) {
    __shared__ float as_[64 * 196];
    __shared__ float ws_[192 * 36];
    __shared__ int rowbase[64];
    const int t = threadIdx.x;
    const size_t base = (size_t)blockIdx.x * 64;
    if (t < 64) {
        int dst = (int)base + t;
        int b = dst / 13824, r1 = dst - b * 13824;
        int d = r1 / 576, h2 = (r1 / 24) % 24, w2 = r1 % 24;
        int dd = (d + 22) % 24, hh = (h2 + 22) % 24, ww = (w2 + 22) % 24;
        int win = ((dd >> 2)*6 + (hh >> 2))*6 + (ww >> 2);
        int n = ((dd & 3) << 4) | ((hh & 3) << 2) | (ww & 3);
        rowbase[t] = ((b*216 + win)*64 + n) * 192;
    }
    __syncthreads();
    #pragma unroll
    for (int i = 0; i < 48; ++i) {
        int j = i*256 + t;
        int r = j / 192, c = j - r * 192;
        as_[r*196 + c] = buf2[rowbase[r] + c];
    }
    const int rg = t >> 3, g = t & 7;
    float acc0[24], acc1[24];
    #pragma unroll
    for (int k = 0; k < 24; ++k) { acc0[k] = 0.f; acc1[k] = 0.f; }
    const float* a0p = as_ + (rg*2) * 196;
    const float* a1p = a0p + 196;
    for (int cb = 0; cb < 6; ++cb) {
        __syncthreads();
        #pragma unroll
        for (int i = 0; i < 24; ++i) {
            int f = i*256 + t;
            int c = f >> 5, j = f & 31;
            ws_[c*36 + j] = pw[c*192 + cb*32 + j];
        }
        __syncthreads();
        #pragma unroll
        for (int j4 = 0; j4 < 8; ++j4) {
            float4 a0 = *reinterpret_cast<const float4*>(a0p + cb*32 + j4*4);
            float4 a1 = *reinterpret_cast<const float4*>(a1p + cb*32 + j4*4);
            #pragma unroll
            for (int k = 0; k < 24; ++k) {
                float4 w4 = *reinterpret_cast<const float4*>(ws_ + (g + 8*k)*36 + j4*4);
                acc0[k] += DOT4(a0, w4);
                acc1[k] += DOT4(a1, w4);
            }
        }
    }
    const size_t dst0 = base + rg*2;
    #pragma unroll
    for (int k = 0; k < 24; ++k) {
        int c = g + 8*k;
        out[dst0*192 + c]     = x[dst0*192 + c]     + acc0[k] + pb[c];
        out[(dst0+1)*192 + c] = x[(dst0+1)*192 + c] + acc1[k] + pb[c];
    }
}

// ---------------- K4: LN2 + FC1 + GELU + FC2 + residual, in place on d_out ----------------
__global__ __launch_bounds__(256) void k_mlp(
        const float* __restrict__ n2w, const float* __restrict__ n2b,
        const float* __restrict__ f1w, const float* __restrict__ f1b,
        const float* __restrict__ f2w, const float* __restrict__ f2b,
        float* out) {
    __shared__ float xs[32 * 196];
    __shared__ float hs[32 * 68];
    const int t = threadIdx.x;
    const size_t base = (size_t)blockIdx.x * 32;
    const int r = t >> 3, g = t & 7;
    {
        const float* hp = out + (base + r) * 192 + g * 24;
        float sum = 0.f, ssum = 0.f;
        #pragma unroll
        for (int j4 = 0; j4 < 6; ++j4) {
            float4 q = reinterpret_cast<const float4*>(hp)[j4];
            sum  += q.x + q.y + q.z + q.w;
            ssum += q.x*q.x + q.y*q.y + q.z*q.z + q.w*q.w;
        }
        sum  += __shfl_xor(sum, 1);  sum  += __shfl_xor(sum, 2);  sum  += __shfl_xor(sum, 4);
        ssum += __shfl_xor(ssum, 1); ssum += __shfl_xor(ssum, 2); ssum += __shfl_xor(ssum, 4);
        float mu = sum * (1.f/192.f);
        float inv = rsqrtf(ssum * (1.f/192.f) - mu*mu + 1e-5f);
        #pragma unroll
        for (int j4 = 0; j4 < 6; ++j4) {
            float4 q = reinterpret_cast<const float4*>(hp)[j4];
            int c = g*24 + j4*4;
            xs[r*196 + c+0] = (q.x - mu)*inv*n2w[c+0] + n2b[c+0];
            xs[r*196 + c+1] = (q.y - mu)*inv*n2w[c+1] + n2b[c+1];
            xs[r*196 + c+2] = (q.z - mu)*inv*n2w[c+2] + n2b[c+2];
            xs[r*196 + c+3] = (q.w - mu)*inv*n2w[c+3] + n2b[c+3];
        }
    }
    const int rg = t & 15, jg = t >> 4;
    float acc[24];
    #pragma unroll
    for (int k = 0; k < 24; ++k) acc[k] = 0.f;
    for (int hb = 0; hb < 768; hb += 64) {
        __syncthreads();
        // hidden chunk: rows 2rg,2rg+1 x hidden jg*4..+3
        float h00=0,h01=0,h02=0,h03=0,h10=0,h11=0,h12=0,h13=0;
        const float4* xr0 = reinterpret_cast<const float4*>(xs + (2*rg)*196);
        const float4* xr1 = reinterpret_cast<const float4*>(xs + (2*rg+1)*196);
        const float4* w0 = reinterpret_cast<const float4*>(f1w + (size_t)(hb + jg*4 + 0)*192);
        const float4* w1 = reinterpret_cast<const float4*>(f1w + (size_t)(hb + jg*4 + 1)*192);
        const float4* w2 = reinterpret_cast<const float4*>(f1w + (size_t)(hb + jg*4 + 2)*192);
        const float4* w3 = reinterpret_cast<const float4*>(f1w + (size_t)(hb + jg*4 + 3)*192);
        for (int c4 = 0; c4 < 48; ++c4) {
            float4 a0 = xr0[c4], a1 = xr1[c4];
            float4 b0 = w0[c4], b1v = w1[c4], b2 = w2[c4], b3 = w3[c4];
            h00 += DOT4(a0, b0); h01 += DOT4(a0, b1v); h02 += DOT4(a0, b2); h03 += DOT4(a0, b3);
            h10 += DOT4(a1, b0); h11 += DOT4(a1, b1v); h12 += DOT4(a1, b2); h13 += DOT4(a1, b3);
        }
        {
            float bb0 = f1b[hb+jg*4+0], bb1 = f1b[hb+jg*4+1], bb2 = f1b[hb+jg*4+2], bb3 = f1b[hb+jg*4+3];
            h00 += bb0; h01 += bb1; h02 += bb2; h03 += bb3;
            h10 += bb0; h11 += bb1; h12 += bb2; h13 += bb3;
            h00 = 0.5f*h00*(1.f + erff(h00*0.70710678118654752f));
            h01 = 0.5f*h01*(1.f + erff(h01*0.70710678118654752f));
            h02 = 0.5f*h02*(1.f + erff(h02*0.70710678118654752f));
            h03 = 0.5f*h03*(1.f + erff(h03*0.70710678118654752f));
            h10 = 0.5f*h10*(1.f + erff(h10*0.70710678118654752f));
            h11 = 0.5f*h11*(1.f + erff(h11*0.70710678118654752f));
            h12 = 0.5f*h12*(1.f + erff(h12*0.70710678118654752f));
            h13 = 0.5f*h13*(1.f + erff(h13*0.70710678118654752f));
            float* hrow0 = hs + (2*rg)*68 + jg*4;
            float* hrow1 = hs + (2*rg+1)*68 + jg*4;
            hrow0[0]=h00; hrow0[1]=h01; hrow0[2]=h02; hrow0[3]=h03;
            hrow1[0]=h10; hrow1[1]=h11; hrow1[2]=h12; hrow1[3]=h13;
        }
        __syncthreads();
        // accumulate: out row r, channels g+8k
        #pragma unroll
        for (int j4 = 0; j4 < 16; ++j4) {
            float4 h4 = *reinterpret_cast<const float4*>(hs + r*68 + j4*4);
            #pragma unroll
            for (int k = 0; k < 24; ++k) {
                float4 w4 = *reinterpret_cast<const float4*>(f2w + (size_t)(g + 8*k)*768 + hb + j4*4);
                acc[k] += DOT4(h4, w4);
            }
        }
    }
    {
        const size_t dst = base + r;
        #pragma unroll
        for (int k = 0; k < 24; ++k) {
            int c = g + 8*k;
            out[dst*192 + c] = out[dst*192 + c] + acc[k] + f2b[c];
        }
    }
}

extern "C" void kernel_launch(void* const* d_in, const int* in_sizes, int n_in,
                              void* d_out, int out_size, void* d_ws, size_t ws_size,
                              hipStream_t stream) {
    const float* x     = (const float*)d_in[0];
    const float* n1w   = (const float*)d_in[1];
    const float* n1b   = (const float*)d_in[2];
    const float* qkvw  = (const float*)d_in[3];
    const float* ls    = (const float*)d_in[6];
    const float* cpw1  = (const float*)d_in[7];
    const float* cpb1  = (const float*)d_in[8];
    const float* cpw2  = (const float*)d_in[9];
    const float* pw    = (const float*)d_in[10];
    const float* pb    = (const float*)d_in[11];
    const float* n2w   = (const float*)d_in[12];
    const float* n2b   = (const float*)d_in[13];
    const float* f1w   = (const float*)d_in[14];
    const float* f1b   = (const float*)d_in[15];
    const float* f2w   = (const float*)d_in[16];
    const float* f2b   = (const float*)d_in[17];
    const float* rtab  = (const float*)d_in[18];
    const int*   ridx  = (const int*)d_in[19];
    const float* amask = (const float*)d_in[20];
    float* out = (float*)d_out;
    float* ws  = (float*)d_ws;

    float* buf1 = ws;                      // 1728*64*192 = 21233664 floats (windowed LN x, c-major per window)
    float* buf2 = ws + 21233664;           // attention output, token-major windowed
    float* tblo = ws + 2*21233664;         // 343*6
    float* b16  = tblo + 2064;             // 6*64*64

    k_cpb_table<<<dim3(9),     dim3(256), 0, stream>>>(rtab, cpw1, cpb1, cpw2, tblo);
    k_bias16   <<<dim3(96),    dim3(256), 0, stream>>>(tblo, ridx, b16);
    k_ln1      <<<dim3(1728),  dim3(256), 0, stream>>>(x, n1w, n1b, buf1);
    k_attn     <<<dim3(10368), dim3(256), 0, stream>>>(buf1, qkvw, ls, b16, amask, buf2);
    k_proj     <<<dim3(1728),  dim3(256), 0, stream>>>(buf2, x, pw, pb, out);
    k_mlp      <<<dim3(3456),  dim3(256), 0, stream>>>(n2w, n2b, f1w, f1b, f2w, f2b, out);
}

// Round 3
// 2250.972 us; speedup vs baseline: 4.3916x; 4.3916x over previous
//
#include <hip/hip_runtime.h>
#include <hip/hip_bf16.h>
#include <math.h>

#define DOT4(a,b) ((a).x*(b).x + (a).y*(b).y + (a).z*(b).z + (a).w*(b).w)

typedef __attribute__((ext_vector_type(8))) short bf16x8;
typedef __attribute__((ext_vector_type(4))) float f32x4;

__device__ inline ushort f2bf(float f) {
    __hip_bfloat16 h = __float2bfloat16(f);
    return *reinterpret_cast<ushort*>(&h);
}

// ---------------- K0a: CPB MLP table: (343,3) -> relu(512) -> (343,6) ----------------
__global__ __launch_bounds__(256) void k_cpb_table(
        const float* __restrict__ rtab, const float* __restrict__ w1,
        const float* __restrict__ b1, const float* __restrict__ w2,
        float* __restrict__ table_out) {
    int idx = blockIdx.x * 256 + threadIdx.x;
    if (idx >= 343 * 6) return;
    int r = idx / 6, head = idx - r * 6;
    float t0 = rtab[r*3+0], t1 = rtab[r*3+1], t2 = rtab[r*3+2];
    float s = 0.f;
    for (int j = 0; j < 512; ++j) {
        float a = t0*w1[j*3+0] + t1*w1[j*3+1] + t2*w1[j*3+2] + b1[j];
        a = fmaxf(a, 0.f);
        s += a * w2[head*512 + j];
    }
    table_out[idx] = s;   // layout [r][head]
}

// ---------------- K0b: gather + 16*sigmoid -> bias16[6][64][64] ----------------
__global__ __launch_bounds__(256) void k_bias16(
        const float* __restrict__ table_out, const int* __restrict__ ridx,
        float* __restrict__ bias16) {
    int idx = blockIdx.x * 256 + threadIdx.x;
    if (idx >= 6 * 64 * 64) return;
    int head = idx >> 12;
    int nm = idx & 4095;
    float v = table_out[ridx[nm] * 6 + head];
    bias16[idx] = 16.f / (1.f + expf(-v));
}

// ---------------- K1: LN1 + roll(-2) + window partition -> buf1 [win][c][n] ----------------
__global__ __launch_bounds__(256) void k_ln1(
        const float* __restrict__ x, const float* __restrict__ nw,
        const float* __restrict__ nb, float* __restrict__ buf1) {
    __shared__ float xs[64 * 193];
    __shared__ float muS[64], invS[64];
    const int wb = blockIdx.x;            // 0..1727
    const int b = wb / 216, win = wb - b * 216;
    const int wdi = win / 36, whi = (win / 6) % 6, wwi = win % 6;
    const int t = threadIdx.x;
    const int n = t >> 2, sub = t & 3;    // 4 lanes per token, 48 ch each
    const int id = n >> 4, ih = (n >> 2) & 3, iw = n & 3;
    const int dsrc = (wdi*4 + id + 2) % 24;
    const int hsrc = (whi*4 + ih + 2) % 24;
    const int wsrc = (wwi*4 + iw + 2) % 24;
    const float* xr = x + (size_t)(((b*24 + dsrc)*24 + hsrc)*24 + wsrc) * 192 + sub*48;
    float sum = 0.f, ssum = 0.f;
    #pragma unroll
    for (int j4 = 0; j4 < 12; ++j4) {
        float4 q = reinterpret_cast<const float4*>(xr)[j4];
        sum  += q.x + q.y + q.z + q.w;
        ssum += q.x*q.x + q.y*q.y + q.z*q.z + q.w*q.w;
        int c = sub*48 + j4*4;
        xs[n*193 + c+0] = q.x;
        xs[n*193 + c+1] = q.y;
        xs[n*193 + c+2] = q.z;
        xs[n*193 + c+3] = q.w;
    }
    sum  += __shfl_xor(sum, 1);  sum  += __shfl_xor(sum, 2);
    ssum += __shfl_xor(ssum, 1); ssum += __shfl_xor(ssum, 2);
    if (sub == 0) {
        float mu = sum * (1.f/192.f);
        float var = ssum * (1.f/192.f) - mu*mu;
        muS[n] = mu;
        invS[n] = rsqrtf(var + 1e-5f);
    }
    __syncthreads();
    float* outp = buf1 + (size_t)wb * 12288;
    #pragma unroll
    for (int i = 0; i < 48; ++i) {
        int j2 = i*256 + t;
        int c = j2 >> 6, nn = j2 & 63;
        outp[j2] = (xs[nn*193 + c] - muS[nn]) * invS[nn] * nw[c] + nb[c];
    }
}

// ---------------- K2: per-(window,head) QKV + cosine attn + bias + mask + softmax + PV ----------------
__global__ __launch_bounds__(256) void k_attn(
        const float* __restrict__ buf1, const float* __restrict__ qkvw,
        const float* __restrict__ ls, const float* __restrict__ bias16,
        const float* __restrict__ amask, float* __restrict__ buf2) {
    __shared__ float qs[64 * 36];
    __shared__ float ks[64 * 36];
    __shared__ float vs[64 * 36];
    __shared__ float at[64 * 68];
    const int bid = blockIdx.x;
    const int wb = bid / 6, head = bid - (bid / 6) * 6;
    const int win = wb % 216;
    const int t = threadIdx.x;

    // ---- QKV: 4 tokens x 6 outputs per thread, c-major window reads ----
    {
        const int ng = t & 15, og = t >> 4;
        const float* bw = buf1 + (size_t)wb * 12288 + ng * 4;
        float acc[4][6];
        #pragma unroll
        for (int a = 0; a < 4; ++a)
            #pragma unroll
            for (int i = 0; i < 6; ++i) acc[a][i] = 0.f;
        const float4* wp[6];
        #pragma unroll
        for (int i = 0; i < 6; ++i) {
            int o = og*6 + i;
            int mat = o >> 5, dh = o & 31;
            wp[i] = reinterpret_cast<const float4*>(qkvw + (size_t)(mat*192 + head*32 + dh) * 192);
        }
        for (int c4 = 0; c4 < 48; ++c4) {
            float4 x0 = *reinterpret_cast<const float4*>(bw + (c4*4+0)*64);
            float4 x1 = *reinterpret_cast<const float4*>(bw + (c4*4+1)*64);
            float4 x2 = *reinterpret_cast<const float4*>(bw + (c4*4+2)*64);
            float4 x3 = *reinterpret_cast<const float4*>(bw + (c4*4+3)*64);
            #pragma unroll
            for (int i = 0; i < 6; ++i) {
                float4 w = wp[i][c4];
                acc[0][i] += x0.x*w.x + x1.x*w.y + x2.x*w.z + x3.x*w.w;
                acc[1][i] += x0.y*w.x + x1.y*w.y + x2.y*w.z + x3.y*w.w;
                acc[2][i] += x0.z*w.x + x1.z*w.y + x2.z*w.z + x3.z*w.w;
                acc[3][i] += x0.w*w.x + x1.w*w.y + x2.w*w.z + x3.w*w.w;
            }
        }
        #pragma unroll
        for (int i = 0; i < 6; ++i) {
            int o = og*6 + i;
            int mat = o >> 5, dh = o & 31;
            float* dst = (mat == 0) ? qs : ((mat == 1) ? ks : vs);
            #pragma unroll
            for (int a = 0; a < 4; ++a)
                dst[(ng*4 + a)*36 + dh] = acc[a][i];
        }
    }
    __syncthreads();

    // ---- normalize q (fold logit scale) and k rows ----
    if (t < 128) {
        const int which = t >> 6, r = t & 63;
        float* p = which ? (ks + r*36) : (qs + r*36);
        float ss = 0.f;
        #pragma unroll
        for (int d4 = 0; d4 < 8; ++d4) {
            float4 q = *reinterpret_cast<const float4*>(p + d4*4);
            ss += DOT4(q, q);
        }
        float f = 1.f / fmaxf(sqrtf(ss), 1e-12f);
        if (which == 0) f *= expf(fminf(ls[head], 4.6051701859880914f));
        #pragma unroll
        for (int d4 = 0; d4 < 8; ++d4) {
            float4 q = *reinterpret_cast<const float4*>(p + d4*4);
            q.x *= f; q.y *= f; q.z *= f; q.w *= f;
            *reinterpret_cast<float4*>(p + d4*4) = q;
        }
    }
    __syncthreads();

    // ---- scores: each thread owns column m, 16 rows ----
    {
        const int m = t & 63, nblk = t >> 6;
        float4 kr[8];
        #pragma unroll
        for (int d4 = 0; d4 < 8; ++d4)
            kr[d4] = *reinterpret_cast<const float4*>(ks + m*36 + d4*4);
        const float* bi = bias16 + head*4096 + m;
        const float* mk = amask + (size_t)win*4096 + m;
        #pragma unroll
        for (int i = 0; i < 16; ++i) {
            int n = i*4 + nblk;
            float s = 0.f;
            #pragma unroll
            for (int d4 = 0; d4 < 8; ++d4) {
                float4 q4 = *reinterpret_cast<const float4*>(qs + n*36 + d4*4);
                s += DOT4(q4, kr[d4]);
            }
            at[n*68 + m] = s + bi[n*64] + mk[n*64];
        }
    }
    __syncthreads();

    // ---- softmax per row (4 lanes per row) ----
    {
        const int r = t >> 2, kq = t & 3;
        float* ar = at + r*68 + kq*16;
        float mx = -1e30f;
        #pragma unroll
        for (int j = 0; j < 16; ++j) mx = fmaxf(mx, ar[j]);
        mx = fmaxf(mx, __shfl_xor(mx, 1));
        mx = fmaxf(mx, __shfl_xor(mx, 2));
        float sm = 0.f;
        #pragma unroll
        for (int j = 0; j < 16; ++j) { float e = expf(ar[j] - mx); ar[j] = e; sm += e; }
        sm += __shfl_xor(sm, 1); sm += __shfl_xor(sm, 2);
        float rs = 1.f / sm;
        #pragma unroll
        for (int j = 0; j < 16; ++j) ar[j] *= rs;
    }
    __syncthreads();

    // ---- PV: thread owns (dh, 8 rows) ----
    {
        const int dh = t & 31, nb2 = t >> 5;
        float accO[8] = {0,0,0,0,0,0,0,0};
        for (int m4 = 0; m4 < 16; ++m4) {
            float v0 = vs[(m4*4+0)*36 + dh];
            float v1 = vs[(m4*4+1)*36 + dh];
            float v2 = vs[(m4*4+2)*36 + dh];
            float v3 = vs[(m4*4+3)*36 + dh];
            #pragma unroll
            for (int i = 0; i < 8; ++i) {
                float4 a4 = *reinterpret_cast<const float4*>(at + (i*8 + nb2)*68 + m4*4);
                accO[i] += a4.x*v0 + a4.y*v1 + a4.z*v2 + a4.w*v3;
            }
        }
        float* op = buf2 + (size_t)wb * 12288 + head*32 + dh;
        #pragma unroll
        for (int i = 0; i < 8; ++i)
            op[(i*8 + nb2) * 192] = accO[i];
    }
}

// ---------------- K3: proj + window reverse + roll(+2) + residual -> d_out ----------------
__global__ __launch_bounds__(256) void k_proj(
        const float* __restrict__ buf2, const float* __restrict__ x,
        const float* __restrict__ pw, const float* __restrict__ pb,
        float* __restrict__ out) {
    __shared__ float as_[64 * 196];
    __shared__ float ws_[192 * 36];
    __shared__ int rowbase[64];
    const int t = threadIdx.x;
    const size_t base = (size_t)blockIdx.x * 64;
    if (t < 64) {
        int dst = (int)base + t;
        int b = dst / 13824, r1 = dst - b * 13824;
        int d = r1 / 576, h2 = (r1 / 24) % 24, w2 = r1 % 24;
        int dd = (d + 22) % 24, hh = (h2 + 22) % 24, ww = (w2 + 22) % 24;
        int win = ((dd >> 2)*6 + (hh >> 2))*6 + (ww >> 2);
        int n = ((dd & 3) << 4) | ((hh & 3) << 2) | (ww & 3);
        rowbase[t] = ((b*216 + win)*64 + n) * 192;
    }
    __syncthreads();
    #pragma unroll
    for (int i = 0; i < 48; ++i) {
        int j = i*256 + t;
        int r = j / 192, c = j - r * 192;
        as_[r*196 + c] = buf2[rowbase[r] + c];
    }
    const int rg = t >> 3, g = t & 7;
    float acc0[24], acc1[24];
    #pragma unroll
    for (int k = 0; k < 24; ++k) { acc0[k] = 0.f; acc1[k] = 0.f; }
    const float* a0p = as_ + (rg*2) * 196;
    const float* a1p = a0p + 196;
    for (int cb = 0; cb < 6; ++cb) {
        __syncthreads();
        #pragma unroll
        for (int i = 0; i < 24; ++i) {
            int f = i*256 + t;
            int c = f >> 5, j = f & 31;
            ws_[c*36 + j] = pw[c*192 + cb*32 + j];
        }
        __syncthreads();
        #pragma unroll
        for (int j4 = 0; j4 < 8; ++j4) {
            float4 a0 = *reinterpret_cast<const float4*>(a0p + cb*32 + j4*4);
            float4 a1 = *reinterpret_cast<const float4*>(a1p + cb*32 + j4*4);
            #pragma unroll
            for (int k = 0; k < 24; ++k) {
                float4 w4 = *reinterpret_cast<const float4*>(ws_ + (g + 8*k)*36 + j4*4);
                acc0[k] += DOT4(a0, w4);
                acc1[k] += DOT4(a1, w4);
            }
        }
    }
    const size_t dst0 = base + rg*2;
    #pragma unroll
    for (int k = 0; k < 24; ++k) {
        int c = g + 8*k;
        out[dst0*192 + c]     = x[dst0*192 + c]     + acc0[k] + pb[c];
        out[(dst0+1)*192 + c] = x[(dst0+1)*192 + c] + acc1[k] + pb[c];
    }
}

// ---------------- K4a: convert MLP weights fp32 -> bf16 ----------------
__global__ __launch_bounds__(256) void k_wcvt(
        const float* __restrict__ f1w, const float* __restrict__ f2w,
        ushort* __restrict__ W1b, ushort* __restrict__ W2b) {
    int i = blockIdx.x * 256 + threadIdx.x;   // grid covers 147456 exactly
    W1b[i] = f2bf(f1w[i]);
    W2b[i] = f2bf(f2w[i]);
}

// ---------------- K4: fused LN2 + FC1 + GELU + FC2 + residual ----------------
// 1728 blocks x 64 tokens (110592 total). 4 waves; wave w owns token stripe [16w,16w+16).
// LN2'd activations bf16 in LDS (stride 200); hidden chunk (128) GELU'd bf16 in LDS
// (stride 136); W1/W2 bf16 fragments read straight from global (L1/L2-resident).
__global__ __launch_bounds__(256) void k_mlp2(
        const ushort* __restrict__ W1b, const ushort* __restrict__ W2b,
        const float* __restrict__ n2w, const float* __restrict__ n2b,
        const float* __restrict__ f1b, const float* __restrict__ f2b,
        float* __restrict__ out) {
    __shared__ ushort As[64 * 200];
    __shared__ ushort Hs[64 * 136];
    const int t = threadIdx.x;
    const size_t tok0 = (size_t)blockIdx.x * 64;

    // ---- LN2 of this block's 64 tokens -> As (bf16); 4 threads/token ----
    {
        const int r = t >> 2, q = t & 3;   // wave w handles rows [16w,16w+16) = its own stripe
        const float* hp = out + (tok0 + r) * 192 + q * 48;
        float4 v[12];
        float sum = 0.f, ssum = 0.f;
        #pragma unroll
        for (int j = 0; j < 12; ++j) {
            v[j] = reinterpret_cast<const float4*>(hp)[j];
            sum  += v[j].x + v[j].y + v[j].z + v[j].w;
            ssum += v[j].x*v[j].x + v[j].y*v[j].y + v[j].z*v[j].z + v[j].w*v[j].w;
        }
        sum  += __shfl_xor(sum, 1);  sum  += __shfl_xor(sum, 2);
        ssum += __shfl_xor(ssum, 1); ssum += __shfl_xor(ssum, 2);
        float mu = sum * (1.f/192.f);
        float inv = rsqrtf(ssum * (1.f/192.f) - mu*mu + 1e-5f);
        #pragma unroll
        for (int j = 0; j < 12; ++j) {
            int c = q*48 + j*4;
            ushort4 o;
            o.x = f2bf((v[j].x - mu)*inv*n2w[c+0] + n2b[c+0]);
            o.y = f2bf((v[j].y - mu)*inv*n2w[c+1] + n2b[c+1]);
            o.z = f2bf((v[j].z - mu)*inv*n2w[c+2] + n2b[c+2]);
            o.w = f2bf((v[j].w - mu)*inv*n2w[c+3] + n2b[c+3]);
            *reinterpret_cast<ushort4*>(As + r*200 + c) = o;
        }
    }
    __syncthreads();

    const int wid = t >> 6, lane = t & 63;
    const int fr = lane & 15, fg = lane >> 4;
    const int trow = wid * 16;
    f32x4 acc2[12] = {};

    for (int hb = 0; hb < 768; hb += 128) {
        // ---- FC1: H[trow..+15][hb..hb+127] ----
        f32x4 acc1[8] = {};
        #pragma unroll
        for (int ks = 0; ks < 6; ++ks) {
            bf16x8 a = *(const bf16x8*)(As + (trow + fr)*200 + ks*32 + fg*8);
            #pragma unroll
            for (int j = 0; j < 8; ++j) {
                bf16x8 b = *(const bf16x8*)(W1b + (size_t)(hb + j*16 + fr)*192 + ks*32 + fg*8);
                acc1[j] = __builtin_amdgcn_mfma_f32_16x16x32_bf16(a, b, acc1[j], 0, 0, 0);
            }
        }
        __syncthreads();
        // ---- bias + GELU -> Hs (C/D map: col=lane&15, row=4*(lane>>4)+reg) ----
        #pragma unroll
        for (int j = 0; j < 8; ++j) {
            float bias = f1b[hb + j*16 + fr];
            #pragma unroll
            for (int e = 0; e < 4; ++e) {
                float h = acc1[j][e] + bias;
                h = 0.5f*h*(1.f + erff(h*0.70710678118654752f));
                Hs[(trow + fg*4 + e)*136 + j*16 + fr] = f2bf(h);
            }
        }
        __syncthreads();
        // ---- FC2 partial over this hidden chunk ----
        #pragma unroll
        for (int ks = 0; ks < 4; ++ks) {
            bf16x8 a = *(const bf16x8*)(Hs + (trow + fr)*136 + ks*32 + fg*8);
            #pragma unroll
            for (int j = 0; j < 12; ++j) {
                bf16x8 b = *(const bf16x8*)(W2b + (size_t)(j*16 + fr)*768 + hb + ks*32 + fg*8);
                acc2[j] = __builtin_amdgcn_mfma_f32_16x16x32_bf16(a, b, acc2[j], 0, 0, 0);
            }
        }
    }

    // ---- epilogue: out += mlp + f2b ----
    #pragma unroll
    for (int j = 0; j < 12; ++j) {
        int c = j*16 + fr;
        float bias = f2b[c];
        #pragma unroll
        for (int e = 0; e < 4; ++e) {
            size_t idx = (tok0 + trow + fg*4 + e)*192 + c;
            out[idx] += acc2[j][e] + bias;
        }
    }
}

extern "C" void kernel_launch(void* const* d_in, const int* in_sizes, int n_in,
                              void* d_out, int out_size, void* d_ws, size_t ws_size,
                              hipStream_t stream) {
    const float* x     = (const float*)d_in[0];
    const float* n1w   = (const float*)d_in[1];
    const float* n1b   = (const float*)d_in[2];
    const float* qkvw  = (const float*)d_in[3];
    const float* ls    = (const float*)d_in[6];
    const float* cpw1  = (const float*)d_in[7];
    const float* cpb1  = (const float*)d_in[8];
    const float* cpw2  = (const float*)d_in[9];
    const float* pw    = (const float*)d_in[10];
    const float* pb    = (const float*)d_in[11];
    const float* n2w   = (const float*)d_in[12];
    const float* n2b   = (const float*)d_in[13];
    const float* f1w   = (const float*)d_in[14];
    const float* f1b   = (const float*)d_in[15];
    const float* f2w   = (const float*)d_in[16];
    const float* f2b   = (const float*)d_in[17];
    const float* rtab  = (const float*)d_in[18];
    const int*   ridx  = (const int*)d_in[19];
    const float* amask = (const float*)d_in[20];
    float* out = (float*)d_out;
    float* ws  = (float*)d_ws;

    float* buf1 = ws;                      // 21233664 floats (windowed LN x, c-major per window)
    float* buf2 = ws + 21233664;           // attention output, token-major windowed
    float* tblo = ws + 2*21233664;         // 343*6
    float* b16  = tblo + 2064;             // 6*64*64

    // MLP weight scratch overlaid into buf1 (dead after k_attn):
    ushort* W1b = (ushort*)buf1;           // 147456
    ushort* W2b = W1b + 147456;            // 147456

    k_cpb_table<<<dim3(9),     dim3(256), 0, stream>>>(rtab, cpw1, cpb1, cpw2, tblo);
    k_bias16   <<<dim3(96),    dim3(256), 0, stream>>>(tblo, ridx, b16);
    k_ln1      <<<dim3(1728),  dim3(256), 0, stream>>>(x, n1w, n1b, buf1);
    k_attn     <<<dim3(10368), dim3(256), 0, stream>>>(buf1, qkvw, ls, b16, amask, buf2);
    k_wcvt     <<<dim3(576),   dim3(256), 0, stream>>>(f1w, f2w, W1b, W2b);
    k_proj     <<<dim3(1728),  dim3(256), 0, stream>>>(buf2, x, pw, pb, out);
    k_mlp2     <<<dim3(1728),  dim3(256), 0, stream>>>(W1b, W2b, n2w, n2b, f1b, f2b, out);
}

// Round 4
// 1487.397 us; speedup vs baseline: 6.6461x; 1.5134x over previous
//
#include <hip/hip_runtime.h>
#include <hip/hip_bf16.h>
#include <math.h>

#define DOT4(a,b) ((a).x*(b).x + (a).y*(b).y + (a).z*(b).z + (a).w*(b).w)

typedef __attribute__((ext_vector_type(8))) short bf16x8;
typedef __attribute__((ext_vector_type(4))) float f32x4;

__device__ inline ushort f2bf(float f) {
    __hip_bfloat16 h = __float2bfloat16(f);
    return *reinterpret_cast<ushort*>(&h);
}

// ---------------- K0a: CPB MLP table: (343,3) -> relu(512) -> (343,6) ----------------
__global__ __launch_bounds__(256) void k_cpb_table(
        const float* __restrict__ rtab, const float* __restrict__ w1,
        const float* __restrict__ b1, const float* __restrict__ w2,
        float* __restrict__ table_out) {
    int idx = blockIdx.x * 256 + threadIdx.x;
    if (idx >= 343 * 6) return;
    int r = idx / 6, head = idx - r * 6;
    float t0 = rtab[r*3+0], t1 = rtab[r*3+1], t2 = rtab[r*3+2];
    float s = 0.f;
    for (int j = 0; j < 512; ++j) {
        float a = t0*w1[j*3+0] + t1*w1[j*3+1] + t2*w1[j*3+2] + b1[j];
        a = fmaxf(a, 0.f);
        s += a * w2[head*512 + j];
    }
    table_out[idx] = s;   // layout [r][head]
}

// ---------------- K0b: gather + 16*sigmoid -> bias16[6][64][64] ----------------
__global__ __launch_bounds__(256) void k_bias16(
        const float* __restrict__ table_out, const int* __restrict__ ridx,
        float* __restrict__ bias16) {
    int idx = blockIdx.x * 256 + threadIdx.x;
    if (idx >= 6 * 64 * 64) return;
    int head = idx >> 12;
    int nm = idx & 4095;
    float v = table_out[ridx[nm] * 6 + head];
    bias16[idx] = 16.f / (1.f + expf(-v));
}

// ---------------- K1: LN1 + roll(-2) + window partition -> buf1 [win][c][n] ----------------
__global__ __launch_bounds__(256) void k_ln1(
        const float* __restrict__ x, const float* __restrict__ nw,
        const float* __restrict__ nb, float* __restrict__ buf1) {
    __shared__ float xs[64 * 193];
    __shared__ float muS[64], invS[64];
    const int wb = blockIdx.x;            // 0..1727
    const int b = wb / 216, win = wb - b * 216;
    const int wdi = win / 36, whi = (win / 6) % 6, wwi = win % 6;
    const int t = threadIdx.x;
    const int n = t >> 2, sub = t & 3;    // 4 lanes per token, 48 ch each
    const int id = n >> 4, ih = (n >> 2) & 3, iw = n & 3;
    const int dsrc = (wdi*4 + id + 2) % 24;
    const int hsrc = (whi*4 + ih + 2) % 24;
    const int wsrc = (wwi*4 + iw + 2) % 24;
    const float* xr = x + (size_t)(((b*24 + dsrc)*24 + hsrc)*24 + wsrc) * 192 + sub*48;
    float sum = 0.f, ssum = 0.f;
    #pragma unroll
    for (int j4 = 0; j4 < 12; ++j4) {
        float4 q = reinterpret_cast<const float4*>(xr)[j4];
        sum  += q.x + q.y + q.z + q.w;
        ssum += q.x*q.x + q.y*q.y + q.z*q.z + q.w*q.w;
        int c = sub*48 + j4*4;
        xs[n*193 + c+0] = q.x;
        xs[n*193 + c+1] = q.y;
        xs[n*193 + c+2] = q.z;
        xs[n*193 + c+3] = q.w;
    }
    sum  += __shfl_xor(sum, 1);  sum  += __shfl_xor(sum, 2);
    ssum += __shfl_xor(ssum, 1); ssum += __shfl_xor(ssum, 2);
    if (sub == 0) {
        float mu = sum * (1.f/192.f);
        float var = ssum * (1.f/192.f) - mu*mu;
        muS[n] = mu;
        invS[n] = rsqrtf(var + 1e-5f);
    }
    __syncthreads();
    float* outp = buf1 + (size_t)wb * 12288;
    #pragma unroll
    for (int i = 0; i < 48; ++i) {
        int j2 = i*256 + t;
        int c = j2 >> 6, nn = j2 & 63;
        outp[j2] = (xs[nn*193 + c] - muS[nn]) * invS[nn] * nw[c] + nb[c];
    }
}

// ---------------- K2: per-(window,head) QKV + cosine attn + bias + mask + softmax + PV ----------------
__global__ __launch_bounds__(256) void k_attn(
        const float* __restrict__ buf1, const float* __restrict__ qkvw,
        const float* __restrict__ ls, const float* __restrict__ bias16,
        const float* __restrict__ amask, ushort* __restrict__ buf2) {
    __shared__ float qs[64 * 36];
    __shared__ float ks[64 * 36];
    __shared__ float vs[64 * 36];
    __shared__ float at[64 * 68];
    const int bid = blockIdx.x;
    const int wb = bid / 6, head = bid - (bid / 6) * 6;
    const int win = wb % 216;
    const int t = threadIdx.x;

    // ---- QKV: 4 tokens x 6 outputs per thread, c-major window reads ----
    {
        const int ng = t & 15, og = t >> 4;
        const float* bw = buf1 + (size_t)wb * 12288 + ng * 4;
        float acc[4][6];
        #pragma unroll
        for (int a = 0; a < 4; ++a)
            #pragma unroll
            for (int i = 0; i < 6; ++i) acc[a][i] = 0.f;
        const float4* wp[6];
        #pragma unroll
        for (int i = 0; i < 6; ++i) {
            int o = og*6 + i;
            int mat = o >> 5, dh = o & 31;
            wp[i] = reinterpret_cast<const float4*>(qkvw + (size_t)(mat*192 + head*32 + dh) * 192);
        }
        for (int c4 = 0; c4 < 48; ++c4) {
            float4 x0 = *reinterpret_cast<const float4*>(bw + (c4*4+0)*64);
            float4 x1 = *reinterpret_cast<const float4*>(bw + (c4*4+1)*64);
            float4 x2 = *reinterpret_cast<const float4*>(bw + (c4*4+2)*64);
            float4 x3 = *reinterpret_cast<const float4*>(bw + (c4*4+3)*64);
            #pragma unroll
            for (int i = 0; i < 6; ++i) {
                float4 w = wp[i][c4];
                acc[0][i] += x0.x*w.x + x1.x*w.y + x2.x*w.z + x3.x*w.w;
                acc[1][i] += x0.y*w.x + x1.y*w.y + x2.y*w.z + x3.y*w.w;
                acc[2][i] += x0.z*w.x + x1.z*w.y + x2.z*w.z + x3.z*w.w;
                acc[3][i] += x0.w*w.x + x1.w*w.y + x2.w*w.z + x3.w*w.w;
            }
        }
        #pragma unroll
        for (int i = 0; i < 6; ++i) {
            int o = og*6 + i;
            int mat = o >> 5, dh = o & 31;
            float* dst = (mat == 0) ? qs : ((mat == 1) ? ks : vs);
            #pragma unroll
            for (int a = 0; a < 4; ++a)
                dst[(ng*4 + a)*36 + dh] = acc[a][i];
        }
    }
    __syncthreads();

    // ---- normalize q (fold logit scale) and k rows ----
    if (t < 128) {
        const int which = t >> 6, r = t & 63;
        float* p = which ? (ks + r*36) : (qs + r*36);
        float ss = 0.f;
        #pragma unroll
        for (int d4 = 0; d4 < 8; ++d4) {
            float4 q = *reinterpret_cast<const float4*>(p + d4*4);
            ss += DOT4(q, q);
        }
        float f = 1.f / fmaxf(sqrtf(ss), 1e-12f);
        if (which == 0) f *= expf(fminf(ls[head], 4.6051701859880914f));
        #pragma unroll
        for (int d4 = 0; d4 < 8; ++d4) {
            float4 q = *reinterpret_cast<const float4*>(p + d4*4);
            q.x *= f; q.y *= f; q.z *= f; q.w *= f;
            *reinterpret_cast<float4*>(p + d4*4) = q;
        }
    }
    __syncthreads();

    // ---- scores: each thread owns column m, 16 rows ----
    {
        const int m = t & 63, nblk = t >> 6;
        float4 kr[8];
        #pragma unroll
        for (int d4 = 0; d4 < 8; ++d4)
            kr[d4] = *reinterpret_cast<const float4*>(ks + m*36 + d4*4);
        const float* bi = bias16 + head*4096 + m;
        const float* mk = amask + (size_t)win*4096 + m;
        #pragma unroll
        for (int i = 0; i < 16; ++i) {
            int n = i*4 + nblk;
            float s = 0.f;
            #pragma unroll
            for (int d4 = 0; d4 < 8; ++d4) {
                float4 q4 = *reinterpret_cast<const float4*>(qs + n*36 + d4*4);
                s += DOT4(q4, kr[d4]);
            }
            at[n*68 + m] = s + bi[n*64] + mk[n*64];
        }
    }
    __syncthreads();

    // ---- softmax per row (4 lanes per row) ----
    {
        const int r = t >> 2, kq = t & 3;
        float* ar = at + r*68 + kq*16;
        float mx = -1e30f;
        #pragma unroll
        for (int j = 0; j < 16; ++j) mx = fmaxf(mx, ar[j]);
        mx = fmaxf(mx, __shfl_xor(mx, 1));
        mx = fmaxf(mx, __shfl_xor(mx, 2));
        float sm = 0.f;
        #pragma unroll
        for (int j = 0; j < 16; ++j) { float e = expf(ar[j] - mx); ar[j] = e; sm += e; }
        sm += __shfl_xor(sm, 1); sm += __shfl_xor(sm, 2);
        float rs = 1.f / sm;
        #pragma unroll
        for (int j = 0; j < 16; ++j) ar[j] *= rs;
    }
    __syncthreads();

    // ---- PV: thread owns (dh, 8 rows); write bf16 ----
    {
        const int dh = t & 31, nb2 = t >> 5;
        float accO[8] = {0,0,0,0,0,0,0,0};
        for (int m4 = 0; m4 < 16; ++m4) {
            float v0 = vs[(m4*4+0)*36 + dh];
            float v1 = vs[(m4*4+1)*36 + dh];
            float v2 = vs[(m4*4+2)*36 + dh];
            float v3 = vs[(m4*4+3)*36 + dh];
            #pragma unroll
            for (int i = 0; i < 8; ++i) {
                float4 a4 = *reinterpret_cast<const float4*>(at + (i*8 + nb2)*68 + m4*4);
                accO[i] += a4.x*v0 + a4.y*v1 + a4.z*v2 + a4.w*v3;
            }
        }
        ushort* op = buf2 + (size_t)wb * 12288 + head*32 + dh;
        #pragma unroll
        for (int i = 0; i < 8; ++i)
            op[(i*8 + nb2) * 192] = f2bf(accO[i]);
    }
}

// ---------------- K4a: convert weights fp32 -> bf16 (fc1, fc2, proj) ----------------
__global__ __launch_bounds__(256) void k_wcvt(
        const float* __restrict__ f1w, const float* __restrict__ f2w,
        const float* __restrict__ pw,
        ushort* __restrict__ W1b, ushort* __restrict__ W2b, ushort* __restrict__ Wpb) {
    int i = blockIdx.x * 256 + threadIdx.x;   // grid covers 147456 exactly
    W1b[i] = f2bf(f1w[i]);
    W2b[i] = f2bf(f2w[i]);
    if (i < 36864) Wpb[i] = f2bf(pw[i]);
}

// ---------------- K3: proj (MFMA bf16) + window reverse + roll(+2) + residual ----------------
// 1728 blocks x 64 dest tokens. Gather window-reversed attn-out rows (bf16) into LDS,
// 4 waves each compute a 16x192 stripe; epilogue coalesced 64B row segments.
__global__ __launch_bounds__(256) void k_proj(
        const ushort* __restrict__ buf2, const float* __restrict__ x,
        const ushort* __restrict__ Wpb, const float* __restrict__ pb,
        float* __restrict__ out) {
    __shared__ ushort As[64 * 200];
    __shared__ int rowbase[64];
    const int t = threadIdx.x;
    const size_t base = (size_t)blockIdx.x * 64;
    if (t < 64) {
        int dst = (int)base + t;
        int b = dst / 13824, r1 = dst - b * 13824;
        int d = r1 / 576, h2 = (r1 / 24) % 24, w2 = r1 % 24;
        int dd = (d + 22) % 24, hh = (h2 + 22) % 24, ww = (w2 + 22) % 24;
        int win = ((dd >> 2)*6 + (hh >> 2))*6 + (ww >> 2);
        int n = ((dd & 3) << 4) | ((hh & 3) << 2) | (ww & 3);
        rowbase[t] = ((b*216 + win)*64 + n) * 192;
    }
    __syncthreads();
    {
        const int r = t >> 2, q = t & 3;
        const ushort* src = buf2 + rowbase[r] + q*48;
        #pragma unroll
        for (int i = 0; i < 6; ++i)
            *(bf16x8*)(As + r*200 + q*48 + i*8) = *(const bf16x8*)(src + i*8);
    }
    __syncthreads();

    const int wid = t >> 6, lane = t & 63;
    const int fr = lane & 15, fg = lane >> 4;
    const int trow = wid * 16;
    f32x4 acc[12] = {};
    #pragma unroll
    for (int ks = 0; ks < 6; ++ks) {
        bf16x8 a = *(const bf16x8*)(As + (trow + fr)*200 + ks*32 + fg*8);
        #pragma unroll
        for (int j = 0; j < 12; ++j) {
            bf16x8 b = *(const bf16x8*)(Wpb + (size_t)(j*16 + fr)*192 + ks*32 + fg*8);
            acc[j] = __builtin_amdgcn_mfma_f32_16x16x32_bf16(a, b, acc[j], 0, 0, 0);
        }
    }
    #pragma unroll
    for (int j = 0; j < 12; ++j) {
        int c = j*16 + fr;
        float bias = pb[c];
        #pragma unroll
        for (int e = 0; e < 4; ++e) {
            size_t idx = (base + trow + fg*4 + e)*192 + c;
            out[idx] = x[idx] + acc[j][e] + bias;
        }
    }
}

// ---------------- K4: fused LN2 + FC1 + GELU + FC2 + residual ----------------
__global__ __launch_bounds__(256) void k_mlp2(
        const ushort* __restrict__ W1b, const ushort* __restrict__ W2b,
        const float* __restrict__ n2w, const float* __restrict__ n2b,
        const float* __restrict__ f1b, const float* __restrict__ f2b,
        float* __restrict__ out) {
    __shared__ ushort As[64 * 200];
    __shared__ ushort Hs[64 * 136];
    const int t = threadIdx.x;
    const size_t tok0 = (size_t)blockIdx.x * 64;

    // ---- LN2 of this block's 64 tokens -> As (bf16); 4 threads/token ----
    {
        const int r = t >> 2, q = t & 3;
        const float* hp = out + (tok0 + r) * 192 + q * 48;
        float4 v[12];
        float sum = 0.f, ssum = 0.f;
        #pragma unroll
        for (int j = 0; j < 12; ++j) {
            v[j] = reinterpret_cast<const float4*>(hp)[j];
            sum  += v[j].x + v[j].y + v[j].z + v[j].w;
            ssum += v[j].x*v[j].x + v[j].y*v[j].y + v[j].z*v[j].z + v[j].w*v[j].w;
        }
        sum  += __shfl_xor(sum, 1);  sum  += __shfl_xor(sum, 2);
        ssum += __shfl_xor(ssum, 1); ssum += __shfl_xor(ssum, 2);
        float mu = sum * (1.f/192.f);
        float inv = rsqrtf(ssum * (1.f/192.f) - mu*mu + 1e-5f);
        #pragma unroll
        for (int j = 0; j < 12; ++j) {
            int c = q*48 + j*4;
            ushort4 o;
            o.x = f2bf((v[j].x - mu)*inv*n2w[c+0] + n2b[c+0]);
            o.y = f2bf((v[j].y - mu)*inv*n2w[c+1] + n2b[c+1]);
            o.z = f2bf((v[j].z - mu)*inv*n2w[c+2] + n2b[c+2]);
            o.w = f2bf((v[j].w - mu)*inv*n2w[c+3] + n2b[c+3]);
            *reinterpret_cast<ushort4*>(As + r*200 + c) = o;
        }
    }
    __syncthreads();

    const int wid = t >> 6, lane = t & 63;
    const int fr = lane & 15, fg = lane >> 4;
    const int trow = wid * 16;
    f32x4 acc2[12] = {};

    for (int hb = 0; hb < 768; hb += 128) {
        // ---- FC1: H[trow..+15][hb..hb+127] ----
        f32x4 acc1[8] = {};
        #pragma unroll
        for (int ks = 0; ks < 6; ++ks) {
            bf16x8 a = *(const bf16x8*)(As + (trow + fr)*200 + ks*32 + fg*8);
            #pragma unroll
            for (int j = 0; j < 8; ++j) {
                bf16x8 b = *(const bf16x8*)(W1b + (size_t)(hb + j*16 + fr)*192 + ks*32 + fg*8);
                acc1[j] = __builtin_amdgcn_mfma_f32_16x16x32_bf16(a, b, acc1[j], 0, 0, 0);
            }
        }
        __syncthreads();
        // ---- bias + GELU -> Hs ----
        #pragma unroll
        for (int j = 0; j < 8; ++j) {
            float bias = f1b[hb + j*16 + fr];
            #pragma unroll
            for (int e = 0; e < 4; ++e) {
                float h = acc1[j][e] + bias;
                h = 0.5f*h*(1.f + erff(h*0.70710678118654752f));
                Hs[(trow + fg*4 + e)*136 + j*16 + fr] = f2bf(h);
            }
        }
        __syncthreads();
        // ---- FC2 partial over this hidden chunk ----
        #pragma unroll
        for (int ks = 0; ks < 4; ++ks) {
            bf16x8 a = *(const bf16x8*)(Hs + (trow + fr)*136 + ks*32 + fg*8);
            #pragma unroll
            for (int j = 0; j < 12; ++j) {
                bf16x8 b = *(const bf16x8*)(W2b + (size_t)(j*16 + fr)*768 + hb + ks*32 + fg*8);
                acc2[j] = __builtin_amdgcn_mfma_f32_16x16x32_bf16(a, b, acc2[j], 0, 0, 0);
            }
        }
    }

    // ---- epilogue: out += mlp + f2b ----
    #pragma unroll
    for (int j = 0; j < 12; ++j) {
        int c = j*16 + fr;
        float bias = f2b[c];
        #pragma unroll
        for (int e = 0; e < 4; ++e) {
            size_t idx = (tok0 + trow + fg*4 + e)*192 + c;
            out[idx] += acc2[j][e] + bias;
        }
    }
}

extern "C" void kernel_launch(void* const* d_in, const int* in_sizes, int n_in,
                              void* d_out, int out_size, void* d_ws, size_t ws_size,
                              hipStream_t stream) {
    const float* x     = (const float*)d_in[0];
    const float* n1w   = (const float*)d_in[1];
    const float* n1b   = (const float*)d_in[2];
    const float* qkvw  = (const float*)d_in[3];
    const float* ls    = (const float*)d_in[6];
    const float* cpw1  = (const float*)d_in[7];
    const float* cpb1  = (const float*)d_in[8];
    const float* cpw2  = (const float*)d_in[9];
    const float* pw    = (const float*)d_in[10];
    const float* pb    = (const float*)d_in[11];
    const float* n2w   = (const float*)d_in[12];
    const float* n2b   = (const float*)d_in[13];
    const float* f1w   = (const float*)d_in[14];
    const float* f1b   = (const float*)d_in[15];
    const float* f2w   = (const float*)d_in[16];
    const float* f2b   = (const float*)d_in[17];
    const float* rtab  = (const float*)d_in[18];
    const int*   ridx  = (const int*)d_in[19];
    const float* amask = (const float*)d_in[20];
    float* out = (float*)d_out;
    float* ws  = (float*)d_ws;

    float* buf1 = ws;                      // 21233664 floats (windowed LN x, c-major per window)
    ushort* buf2 = (ushort*)(ws + 21233664); // attention output bf16, token-major windowed
    float* tblo = ws + 2*21233664;         // 343*6
    float* b16  = tblo + 2064;             // 6*64*64

    // Weight scratch overlaid into buf1 (dead after k_attn):
    ushort* W1b = (ushort*)buf1;           // 147456
    ushort* W2b = W1b + 147456;            // 147456
    ushort* Wpb = W2b + 147456;            // 36864

    k_cpb_table<<<dim3(9),     dim3(256), 0, stream>>>(rtab, cpw1, cpb1, cpw2, tblo);
    k_bias16   <<<dim3(96),    dim3(256), 0, stream>>>(tblo, ridx, b16);
    k_ln1      <<<dim3(1728),  dim3(256), 0, stream>>>(x, n1w, n1b, buf1);
    k_attn     <<<dim3(10368), dim3(256), 0, stream>>>(buf1, qkvw, ls, b16, amask, buf2);
    k_wcvt     <<<dim3(576),   dim3(256), 0, stream>>>(f1w, f2w, pw, W1b, W2b, Wpb);
    k_proj     <<<dim3(1728),  dim3(256), 0, stream>>>(buf2, x, Wpb, pb, out);
    k_mlp2     <<<dim3(1728),  dim3(256), 0, stream>>>(W1b, W2b, n2w, n2b, f1b, f2b, out);
}

// Round 5
// 1150.394 us; speedup vs baseline: 8.5930x; 1.2929x over previous
//
#include <hip/hip_runtime.h>
#include <hip/hip_bf16.h>
#include <math.h>

typedef __attribute__((ext_vector_type(8))) short bf16x8;
typedef __attribute__((ext_vector_type(4))) float f32x4;

__device__ inline ushort f2bf(float f) {
    __hip_bfloat16 h = __float2bfloat16(f);
    return *reinterpret_cast<ushort*>(&h);
}
__device__ inline float bf2f(ushort u) {
    return __uint_as_float(((unsigned int)u) << 16);
}

// ---------------- K0a: CPB MLP table: (343,3) -> relu(512) -> (343,6) ----------------
__global__ __launch_bounds__(256) void k_cpb_table(
        const float* __restrict__ rtab, const float* __restrict__ w1,
        const float* __restrict__ b1, const float* __restrict__ w2,
        float* __restrict__ table_out) {
    int idx = blockIdx.x * 256 + threadIdx.x;
    if (idx >= 343 * 6) return;
    int r = idx / 6, head = idx - r * 6;
    float t0 = rtab[r*3+0], t1 = rtab[r*3+1], t2 = rtab[r*3+2];
    float s = 0.f;
    for (int j = 0; j < 512; ++j) {
        float a = t0*w1[j*3+0] + t1*w1[j*3+1] + t2*w1[j*3+2] + b1[j];
        a = fmaxf(a, 0.f);
        s += a * w2[head*512 + j];
    }
    table_out[idx] = s;   // layout [r][head]
}

// ---------------- K0b: gather + 16*sigmoid -> bias16[6][64][64] ----------------
__global__ __launch_bounds__(256) void k_bias16(
        const float* __restrict__ table_out, const int* __restrict__ ridx,
        float* __restrict__ bias16) {
    int idx = blockIdx.x * 256 + threadIdx.x;
    if (idx >= 6 * 64 * 64) return;
    int head = idx >> 12;
    int nm = idx & 4095;
    float v = table_out[ridx[nm] * 6 + head];
    bias16[idx] = 16.f / (1.f + expf(-v));
}

// ---------------- K0c: convert weights fp32 -> bf16 (qkv, fc1, fc2, proj) ----------------
__global__ __launch_bounds__(256) void k_wcvt(
        const float* __restrict__ qkvw, const float* __restrict__ f1w,
        const float* __restrict__ f2w, const float* __restrict__ pw,
        ushort* __restrict__ Wqb, ushort* __restrict__ W1b,
        ushort* __restrict__ W2b, ushort* __restrict__ Wpb) {
    int i = blockIdx.x * 256 + threadIdx.x;   // 576*256 = 147456 threads
    W1b[i] = f2bf(f1w[i]);
    W2b[i] = f2bf(f2w[i]);
    if (i < 110592) Wqb[i] = f2bf(qkvw[i]);
    if (i < 36864)  Wpb[i] = f2bf(pw[i]);
}

// ---------------- K1: LN1 + roll(-2) + window partition -> buf1 bf16 [win][n][c] ----------------
__global__ __launch_bounds__(256) void k_ln1(
        const float* __restrict__ x, const float* __restrict__ nw,
        const float* __restrict__ nb, ushort* __restrict__ buf1) {
    const int wb = blockIdx.x;            // 0..1727
    const int b = wb / 216, win = wb - b * 216;
    const int wdi = win / 36, whi = (win / 6) % 6, wwi = win % 6;
    const int t = threadIdx.x;
    const int n = t >> 2, sub = t & 3;    // 4 lanes per token, 48 ch each
    const int id = n >> 4, ih = (n >> 2) & 3, iw = n & 3;
    const int dsrc = (wdi*4 + id + 2) % 24;
    const int hsrc = (whi*4 + ih + 2) % 24;
    const int wsrc = (wwi*4 + iw + 2) % 24;
    const float* xr = x + (size_t)(((b*24 + dsrc)*24 + hsrc)*24 + wsrc) * 192 + sub*48;
    float4 q[12];
    float sum = 0.f, ssum = 0.f;
    #pragma unroll
    for (int j = 0; j < 12; ++j) {
        q[j] = reinterpret_cast<const float4*>(xr)[j];
        sum  += q[j].x + q[j].y + q[j].z + q[j].w;
        ssum += q[j].x*q[j].x + q[j].y*q[j].y + q[j].z*q[j].z + q[j].w*q[j].w;
    }
    sum  += __shfl_xor(sum, 1);  sum  += __shfl_xor(sum, 2);
    ssum += __shfl_xor(ssum, 1); ssum += __shfl_xor(ssum, 2);
    float mu = sum * (1.f/192.f);
    float inv = rsqrtf(ssum * (1.f/192.f) - mu*mu + 1e-5f);
    ushort* op = buf1 + ((size_t)wb*64 + n)*192 + sub*48;
    #pragma unroll
    for (int j = 0; j < 12; ++j) {
        int c = sub*48 + j*4;
        ushort4 o;
        o.x = f2bf((q[j].x - mu)*inv*nw[c+0] + nb[c+0]);
        o.y = f2bf((q[j].y - mu)*inv*nw[c+1] + nb[c+1]);
        o.z = f2bf((q[j].z - mu)*inv*nw[c+2] + nb[c+2]);
        o.w = f2bf((q[j].w - mu)*inv*nw[c+3] + nb[c+3]);
        *reinterpret_cast<ushort4*>(op + j*4) = o;
    }
}

// ---------------- K2: fused QKV (MFMA) + cosine attn + bias + mask + softmax + PV ----------------
// 1728 blocks (one window), 4 waves. Two head-groups of 3; per group:
// QKV GEMM (A=window bf16 from global, B=Wqb from L2) -> LDS; fp32 row-norm;
// per-head QK^T/softmax/PV all-MFMA, wave-private P (no barriers in head loop).
__global__ __launch_bounds__(256) void k_attn3(
        const ushort* __restrict__ buf1, const ushort* __restrict__ Wqb,
        const float* __restrict__ ls, const float* __restrict__ bias16,
        const float* __restrict__ amask, ushort* __restrict__ buf2) {
    __shared__ ushort QK[2][3][64][40];   // [q/k][head][n][d pad40]  30720 B
    __shared__ ushort Vt[3][32][72];      // [head][d][n pad72]       13824 B
    __shared__ ushort Pl[4][16][72];      // per-wave P rows          9216 B
    const int wb = blockIdx.x;
    const int win = wb % 216;
    const int t = threadIdx.x;
    const int wid = t >> 6, lane = t & 63;
    const int fr = lane & 15, fg = lane >> 4;
    const int trow = wid * 16;
    const ushort* Abase = buf1 + (size_t)wb * 12288 + (size_t)(trow + fr) * 192 + fg * 8;

    for (int g = 0; g < 2; ++g) {
        if (g) __syncthreads();
        // ---- QKV GEMM for heads g*3..g*3+2: 18 col-tiles (Q:6, K:6, V:6) ----
        f32x4 acc[18] = {};
        #pragma unroll
        for (int ks = 0; ks < 6; ++ks) {
            bf16x8 a = *(const bf16x8*)(Abase + ks*32);
            #pragma unroll
            for (int ct = 0; ct < 18; ++ct) {
                const int seg = ct / 6, u = ct % 6;
                const int gcol = seg*192 + g*96 + u*16;
                bf16x8 b = *(const bf16x8*)(Wqb + (size_t)(gcol + fr)*192 + ks*32 + fg*8);
                acc[ct] = __builtin_amdgcn_mfma_f32_16x16x32_bf16(a, b, acc[ct], 0, 0, 0);
            }
        }
        // ---- epilogue -> LDS (Q/K [n][d], V transposed [d][n]) ----
        #pragma unroll
        for (int ct = 0; ct < 18; ++ct) {
            const int seg = ct / 6, u = ct % 6;
            const int hl = u >> 1, dp = u & 1;
            if (seg < 2) {
                #pragma unroll
                for (int e = 0; e < 4; ++e)
                    QK[seg][hl][trow + fg*4 + e][dp*16 + fr] = f2bf(acc[ct][e]);
            } else {
                ushort4 v4;
                v4.x = f2bf(acc[ct][0]); v4.y = f2bf(acc[ct][1]);
                v4.z = f2bf(acc[ct][2]); v4.w = f2bf(acc[ct][3]);
                *reinterpret_cast<ushort4*>(&Vt[hl][dp*16 + fr][trow + fg*4]) = v4;
            }
        }
        __syncthreads();
        // ---- normalize Q (fold logit scale) and K rows, fp32 ----
        {
            float scq[3];
            #pragma unroll
            for (int hl = 0; hl < 3; ++hl)
                scq[hl] = expf(fminf(ls[g*3 + hl], 4.6051701859880914f));
            for (int rr = t; rr < 384; rr += 256) {
                const int mat = rr / 192, rem = rr - mat*192;
                const int hl = rem >> 6, n = rem & 63;
                ushort* p = &QK[mat][hl][n][0];
                float vals[32];
                float ss = 0.f;
                #pragma unroll
                for (int j = 0; j < 8; ++j) {
                    ushort4 u4 = *reinterpret_cast<const ushort4*>(p + j*4);
                    float a0 = bf2f(u4.x), a1 = bf2f(u4.y), a2 = bf2f(u4.z), a3 = bf2f(u4.w);
                    vals[j*4+0]=a0; vals[j*4+1]=a1; vals[j*4+2]=a2; vals[j*4+3]=a3;
                    ss += a0*a0 + a1*a1 + a2*a2 + a3*a3;
                }
                float f = 1.f / fmaxf(sqrtf(ss), 1e-12f);
                if (mat == 0) f *= (hl == 0 ? scq[0] : (hl == 1 ? scq[1] : scq[2]));
                #pragma unroll
                for (int j = 0; j < 8; ++j) {
                    ushort4 o;
                    o.x = f2bf(vals[j*4+0]*f); o.y = f2bf(vals[j*4+1]*f);
                    o.z = f2bf(vals[j*4+2]*f); o.w = f2bf(vals[j*4+3]*f);
                    *reinterpret_cast<ushort4*>(p + j*4) = o;
                }
            }
        }
        __syncthreads();
        // ---- per-head attention; wave-private rows [trow, trow+16) ----
        #pragma unroll 1
        for (int hl = 0; hl < 3; ++hl) {
            const int h = g*3 + hl;
            // QK^T: 4 MFMA
            bf16x8 qf = *(const bf16x8*)&QK[0][hl][trow + fr][fg*8];
            f32x4 accS[4] = {};
            #pragma unroll
            for (int j = 0; j < 4; ++j) {
                bf16x8 kf = *(const bf16x8*)&QK[1][hl][j*16 + fr][fg*8];
                accS[j] = __builtin_amdgcn_mfma_f32_16x16x32_bf16(qf, kf, accS[j], 0, 0, 0);
            }
            // bias + mask
            float s[4][4];
            const float* bi = bias16 + h*4096;
            const float* mk = amask + (size_t)win*4096;
            #pragma unroll
            for (int e = 0; e < 4; ++e) {
                const int r = trow + fg*4 + e;
                #pragma unroll
                for (int j = 0; j < 4; ++j) {
                    const int c = j*16 + fr;
                    s[j][e] = accS[j][e] + bi[r*64 + c] + mk[r*64 + c];
                }
            }
            // softmax rows (reduce across fr lanes), write P bf16
            #pragma unroll
            for (int e = 0; e < 4; ++e) {
                float m0 = fmaxf(fmaxf(s[0][e], s[1][e]), fmaxf(s[2][e], s[3][e]));
                m0 = fmaxf(m0, __shfl_xor(m0, 1));
                m0 = fmaxf(m0, __shfl_xor(m0, 2));
                m0 = fmaxf(m0, __shfl_xor(m0, 4));
                m0 = fmaxf(m0, __shfl_xor(m0, 8));
                float s0 = 0.f;
                #pragma unroll
                for (int j = 0; j < 4; ++j) { s[j][e] = expf(s[j][e] - m0); s0 += s[j][e]; }
                s0 += __shfl_xor(s0, 1);
                s0 += __shfl_xor(s0, 2);
                s0 += __shfl_xor(s0, 4);
                s0 += __shfl_xor(s0, 8);
                const float rs = 1.f / s0;
                #pragma unroll
                for (int j = 0; j < 4; ++j)
                    Pl[wid][fg*4 + e][j*16 + fr] = f2bf(s[j][e] * rs);
            }
            // PV: 4 MFMA (K=64 in 2 steps, 2 d-tiles)
            f32x4 accO[2] = {};
            #pragma unroll
            for (int kk = 0; kk < 2; ++kk) {
                bf16x8 pa = *(const bf16x8*)&Pl[wid][fr][kk*32 + fg*8];
                #pragma unroll
                for (int j = 0; j < 2; ++j) {
                    bf16x8 vb = *(const bf16x8*)&Vt[hl][j*16 + fr][kk*32 + fg*8];
                    accO[j] = __builtin_amdgcn_mfma_f32_16x16x32_bf16(pa, vb, accO[j], 0, 0, 0);
                }
            }
            // O -> buf2 bf16 [wb][n][192]
            #pragma unroll
            for (int j = 0; j < 2; ++j) {
                #pragma unroll
                for (int e = 0; e < 4; ++e) {
                    buf2[(size_t)wb*12288 + (size_t)(trow + fg*4 + e)*192 + h*32 + j*16 + fr]
                        = f2bf(accO[j][e]);
                }
            }
        }
    }
}

// ---------------- K3: proj (MFMA bf16) + window reverse + roll(+2) + residual ----------------
__global__ __launch_bounds__(256) void k_proj(
        const ushort* __restrict__ buf2, const float* __restrict__ x,
        const ushort* __restrict__ Wpb, const float* __restrict__ pb,
        float* __restrict__ out) {
    __shared__ ushort As[64 * 200];
    __shared__ int rowbase[64];
    const int t = threadIdx.x;
    const size_t base = (size_t)blockIdx.x * 64;
    if (t < 64) {
        int dst = (int)base + t;
        int b = dst / 13824, r1 = dst - b * 13824;
        int d = r1 / 576, h2 = (r1 / 24) % 24, w2 = r1 % 24;
        int dd = (d + 22) % 24, hh = (h2 + 22) % 24, ww = (w2 + 22) % 24;
        int win = ((dd >> 2)*6 + (hh >> 2))*6 + (ww >> 2);
        int n = ((dd & 3) << 4) | ((hh & 3) << 2) | (ww & 3);
        rowbase[t] = ((b*216 + win)*64 + n) * 192;
    }
    __syncthreads();
    {
        const int r = t >> 2, q = t & 3;
        const ushort* src = buf2 + rowbase[r] + q*48;
        #pragma unroll
        for (int i = 0; i < 6; ++i)
            *(bf16x8*)(As + r*200 + q*48 + i*8) = *(const bf16x8*)(src + i*8);
    }
    __syncthreads();

    const int wid = t >> 6, lane = t & 63;
    const int fr = lane & 15, fg = lane >> 4;
    const int trow = wid * 16;
    f32x4 acc[12] = {};
    #pragma unroll
    for (int ks = 0; ks < 6; ++ks) {
        bf16x8 a = *(const bf16x8*)(As + (trow + fr)*200 + ks*32 + fg*8);
        #pragma unroll
        for (int j = 0; j < 12; ++j) {
            bf16x8 b = *(const bf16x8*)(Wpb + (size_t)(j*16 + fr)*192 + ks*32 + fg*8);
            acc[j] = __builtin_amdgcn_mfma_f32_16x16x32_bf16(a, b, acc[j], 0, 0, 0);
        }
    }
    #pragma unroll
    for (int j = 0; j < 12; ++j) {
        int c = j*16 + fr;
        float bias = pb[c];
        #pragma unroll
        for (int e = 0; e < 4; ++e) {
            size_t idx = (base + trow + fg*4 + e)*192 + c;
            out[idx] = x[idx] + acc[j][e] + bias;
        }
    }
}

// ---------------- K4: fused LN2 + FC1 + GELU + FC2 + residual ----------------
__global__ __launch_bounds__(256) void k_mlp2(
        const ushort* __restrict__ W1b, const ushort* __restrict__ W2b,
        const float* __restrict__ n2w, const float* __restrict__ n2b,
        const float* __restrict__ f1b, const float* __restrict__ f2b,
        float* __restrict__ out) {
    __shared__ ushort As[64 * 200];
    __shared__ ushort Hs[64 * 136];
    const int t = threadIdx.x;
    const size_t tok0 = (size_t)blockIdx.x * 64;

    {
        const int r = t >> 2, q = t & 3;
        const float* hp = out + (tok0 + r) * 192 + q * 48;
        float4 v[12];
        float sum = 0.f, ssum = 0.f;
        #pragma unroll
        for (int j = 0; j < 12; ++j) {
            v[j] = reinterpret_cast<const float4*>(hp)[j];
            sum  += v[j].x + v[j].y + v[j].z + v[j].w;
            ssum += v[j].x*v[j].x + v[j].y*v[j].y + v[j].z*v[j].z + v[j].w*v[j].w;
        }
        sum  += __shfl_xor(sum, 1);  sum  += __shfl_xor(sum, 2);
        ssum += __shfl_xor(ssum, 1); ssum += __shfl_xor(ssum, 2);
        float mu = sum * (1.f/192.f);
        float inv = rsqrtf(ssum * (1.f/192.f) - mu*mu + 1e-5f);
        #pragma unroll
        for (int j = 0; j < 12; ++j) {
            int c = q*48 + j*4;
            ushort4 o;
            o.x = f2bf((v[j].x - mu)*inv*n2w[c+0] + n2b[c+0]);
            o.y = f2bf((v[j].y - mu)*inv*n2w[c+1] + n2b[c+1]);
            o.z = f2bf((v[j].z - mu)*inv*n2w[c+2] + n2b[c+2]);
            o.w = f2bf((v[j].w - mu)*inv*n2w[c+3] + n2b[c+3]);
            *reinterpret_cast<ushort4*>(As + r*200 + c) = o;
        }
    }
    __syncthreads();

    const int wid = t >> 6, lane = t & 63;
    const int fr = lane & 15, fg = lane >> 4;
    const int trow = wid * 16;
    f32x4 acc2[12] = {};

    for (int hb = 0; hb < 768; hb += 128) {
        f32x4 acc1[8] = {};
        #pragma unroll
        for (int ks = 0; ks < 6; ++ks) {
            bf16x8 a = *(const bf16x8*)(As + (trow + fr)*200 + ks*32 + fg*8);
            #pragma unroll
            for (int j = 0; j < 8; ++j) {
                bf16x8 b = *(const bf16x8*)(W1b + (size_t)(hb + j*16 + fr)*192 + ks*32 + fg*8);
                acc1[j] = __builtin_amdgcn_mfma_f32_16x16x32_bf16(a, b, acc1[j], 0, 0, 0);
            }
        }
        __syncthreads();
        #pragma unroll
        for (int j = 0; j < 8; ++j) {
            float bias = f1b[hb + j*16 + fr];
            #pragma unroll
            for (int e = 0; e < 4; ++e) {
                float h = acc1[j][e] + bias;
                h = 0.5f*h*(1.f + erff(h*0.70710678118654752f));
                Hs[(trow + fg*4 + e)*136 + j*16 + fr] = f2bf(h);
            }
        }
        __syncthreads();
        #pragma unroll
        for (int ks = 0; ks < 4; ++ks) {
            bf16x8 a = *(const bf16x8*)(Hs + (trow + fr)*136 + ks*32 + fg*8);
            #pragma unroll
            for (int j = 0; j < 12; ++j) {
                bf16x8 b = *(const bf16x8*)(W2b + (size_t)(j*16 + fr)*768 + hb + ks*32 + fg*8);
                acc2[j] = __builtin_amdgcn_mfma_f32_16x16x32_bf16(a, b, acc2[j], 0, 0, 0);
            }
        }
    }

    #pragma unroll
    for (int j = 0; j < 12; ++j) {
        int c = j*16 + fr;
        float bias = f2b[c];
        #pragma unroll
        for (int e = 0; e < 4; ++e) {
            size_t idx = (tok0 + trow + fg*4 + e)*192 + c;
            out[idx] += acc2[j][e] + bias;
        }
    }
}

extern "C" void kernel_launch(void* const* d_in, const int* in_sizes, int n_in,
                              void* d_out, int out_size, void* d_ws, size_t ws_size,
                              hipStream_t stream) {
    const float* x     = (const float*)d_in[0];
    const float* n1w   = (const float*)d_in[1];
    const float* n1b   = (const float*)d_in[2];
    const float* qkvw  = (const float*)d_in[3];
    const float* ls    = (const float*)d_in[6];
    const float* cpw1  = (const float*)d_in[7];
    const float* cpb1  = (const float*)d_in[8];
    const float* cpw2  = (const float*)d_in[9];
    const float* pw    = (const float*)d_in[10];
    const float* pb    = (const float*)d_in[11];
    const float* n2w   = (const float*)d_in[12];
    const float* n2b   = (const float*)d_in[13];
    const float* f1w   = (const float*)d_in[14];
    const float* f1b   = (const float*)d_in[15];
    const float* f2w   = (const float*)d_in[16];
    const float* f2b   = (const float*)d_in[17];
    const float* rtab  = (const float*)d_in[18];
    const int*   ridx  = (const int*)d_in[19];
    const float* amask = (const float*)d_in[20];
    float* out = (float*)d_out;

    // ws layout (all bf16/ushort unless noted); total ~86 MB
    ushort* buf1 = (ushort*)d_ws;          // 21233664 (LN1'd x, [win][n][c])
    ushort* buf2 = buf1 + 21233664;        // 21233664 (attn out, [win][n][c])
    ushort* Wqb  = buf2 + 21233664;        // 110592
    ushort* W1b  = Wqb + 110592;           // 147456
    ushort* W2b  = W1b + 147456;           // 147456
    ushort* Wpb  = W2b + 147456;           // 36864
    float*  tblo = (float*)(Wpb + 36864);  // 2058 (+pad)
    float*  b16  = tblo + 2064;            // 24576

    k_cpb_table<<<dim3(9),    dim3(256), 0, stream>>>(rtab, cpw1, cpb1, cpw2, tblo);
    k_bias16   <<<dim3(96),   dim3(256), 0, stream>>>(tblo, ridx, b16);
    k_wcvt     <<<dim3(576),  dim3(256), 0, stream>>>(qkvw, f1w, f2w, pw, Wqb, W1b, W2b, Wpb);
    k_ln1      <<<dim3(1728), dim3(256), 0, stream>>>(x, n1w, n1b, buf1);
    k_attn3    <<<dim3(1728), dim3(256), 0, stream>>>(buf1, Wqb, ls, b16, amask, buf2);
    k_proj     <<<dim3(1728), dim3(256), 0, stream>>>(buf2, x, Wpb, pb, out);
    k_mlp2     <<<dim3(1728), dim3(256), 0, stream>>>(W1b, W2b, n2w, n2b, f1b, f2b, out);
}

// Round 6
// 966.718 us; speedup vs baseline: 10.2256x; 1.1900x over previous
//
#include <hip/hip_runtime.h>
#include <hip/hip_bf16.h>
#include <math.h>

typedef __attribute__((ext_vector_type(8))) short bf16x8;
typedef __attribute__((ext_vector_type(4))) float f32x4;

__device__ inline ushort f2bf(float f) {
    __hip_bfloat16 h = __float2bfloat16(f);
    return *reinterpret_cast<ushort*>(&h);
}
__device__ inline float bf2f(ushort u) {
    return __uint_as_float(((unsigned int)u) << 16);
}

// ---------------- K0a: CPB MLP table: (343,3) -> relu(512) -> (343,6) ----------------
__global__ __launch_bounds__(256) void k_cpb_table(
        const float* __restrict__ rtab, const float* __restrict__ w1,
        const float* __restrict__ b1, const float* __restrict__ w2,
        float* __restrict__ table_out) {
    int idx = blockIdx.x * 256 + threadIdx.x;
    if (idx >= 343 * 6) return;
    int r = idx / 6, head = idx - r * 6;
    float t0 = rtab[r*3+0], t1 = rtab[r*3+1], t2 = rtab[r*3+2];
    float s = 0.f;
    for (int j = 0; j < 512; ++j) {
        float a = t0*w1[j*3+0] + t1*w1[j*3+1] + t2*w1[j*3+2] + b1[j];
        a = fmaxf(a, 0.f);
        s += a * w2[head*512 + j];
    }
    table_out[idx] = s;   // layout [r][head]
}

// ---------------- K0b: gather + 16*sigmoid -> bias16[6][64][64] ----------------
__global__ __launch_bounds__(256) void k_bias16(
        const float* __restrict__ table_out, const int* __restrict__ ridx,
        float* __restrict__ bias16) {
    int idx = blockIdx.x * 256 + threadIdx.x;
    if (idx >= 6 * 64 * 64) return;
    int head = idx >> 12;
    int nm = idx & 4095;
    float v = table_out[ridx[nm] * 6 + head];
    bias16[idx] = 16.f / (1.f + expf(-v));
}

// ---------------- K0c: convert weights fp32 -> bf16 (qkv, fc1, fc2, proj) ----------------
__global__ __launch_bounds__(256) void k_wcvt(
        const float* __restrict__ qkvw, const float* __restrict__ f1w,
        const float* __restrict__ f2w, const float* __restrict__ pw,
        ushort* __restrict__ Wqb, ushort* __restrict__ W1b,
        ushort* __restrict__ W2b, ushort* __restrict__ Wpb) {
    int i = blockIdx.x * 256 + threadIdx.x;   // 576*256 = 147456 threads
    W1b[i] = f2bf(f1w[i]);
    W2b[i] = f2bf(f2w[i]);
    if (i < 110592) Wqb[i] = f2bf(qkvw[i]);
    if (i < 36864)  Wpb[i] = f2bf(pw[i]);
}

// ---------------- K1: LN1 + roll(-2) + window partition -> buf1 bf16 [win][n][c] ----------------
__global__ __launch_bounds__(256) void k_ln1(
        const float* __restrict__ x, const float* __restrict__ nw,
        const float* __restrict__ nb, ushort* __restrict__ buf1) {
    const int wb = blockIdx.x;            // 0..1727
    const int b = wb / 216, win = wb - b * 216;
    const int wdi = win / 36, whi = (win / 6) % 6, wwi = win % 6;
    const int t = threadIdx.x;
    const int n = t >> 2, sub = t & 3;    // 4 lanes per token, 48 ch each
    const int id = n >> 4, ih = (n >> 2) & 3, iw = n & 3;
    const int dsrc = (wdi*4 + id + 2) % 24;
    const int hsrc = (whi*4 + ih + 2) % 24;
    const int wsrc = (wwi*4 + iw + 2) % 24;
    const float* xr = x + (size_t)(((b*24 + dsrc)*24 + hsrc)*24 + wsrc) * 192 + sub*48;
    float4 q[12];
    float sum = 0.f, ssum = 0.f;
    #pragma unroll
    for (int j = 0; j < 12; ++j) {
        q[j] = reinterpret_cast<const float4*>(xr)[j];
        sum  += q[j].x + q[j].y + q[j].z + q[j].w;
        ssum += q[j].x*q[j].x + q[j].y*q[j].y + q[j].z*q[j].z + q[j].w*q[j].w;
    }
    sum  += __shfl_xor(sum, 1);  sum  += __shfl_xor(sum, 2);
    ssum += __shfl_xor(ssum, 1); ssum += __shfl_xor(ssum, 2);
    float mu = sum * (1.f/192.f);
    float inv = rsqrtf(ssum * (1.f/192.f) - mu*mu + 1e-5f);
    ushort* op = buf1 + ((size_t)wb*64 + n)*192 + sub*48;
    #pragma unroll
    for (int j = 0; j < 12; ++j) {
        int c = sub*48 + j*4;
        ushort4 o;
        o.x = f2bf((q[j].x - mu)*inv*nw[c+0] + nb[c+0]);
        o.y = f2bf((q[j].y - mu)*inv*nw[c+1] + nb[c+1]);
        o.z = f2bf((q[j].z - mu)*inv*nw[c+2] + nb[c+2]);
        o.w = f2bf((q[j].w - mu)*inv*nw[c+3] + nb[c+3]);
        *reinterpret_cast<ushort4*>(op + j*4) = o;
    }
}

// ---------------- K2: fused QKV (MFMA) + cosine attn + bias + mask + softmax + PV ----------------
__global__ __launch_bounds__(256) void k_attn3(
        const ushort* __restrict__ buf1, const ushort* __restrict__ Wqb,
        const float* __restrict__ ls, const float* __restrict__ bias16,
        const float* __restrict__ amask, ushort* __restrict__ buf2) {
    __shared__ ushort QK[2][3][64][40];   // [q/k][head][n][d pad40]  30720 B
    __shared__ ushort Vt[3][32][72];      // [head][d][n pad72]       13824 B
    __shared__ ushort Pl[4][16][72];      // per-wave P rows          9216 B
    const int wb = blockIdx.x;
    const int win = wb % 216;
    const int t = threadIdx.x;
    const int wid = t >> 6, lane = t & 63;
    const int fr = lane & 15, fg = lane >> 4;
    const int trow = wid * 16;
    const ushort* Abase = buf1 + (size_t)wb * 12288 + (size_t)(trow + fr) * 192 + fg * 8;

    for (int g = 0; g < 2; ++g) {
        if (g) __syncthreads();
        // ---- QKV GEMM for heads g*3..g*3+2: 18 col-tiles (Q:6, K:6, V:6) ----
        f32x4 acc[18] = {};
        #pragma unroll
        for (int ks = 0; ks < 6; ++ks) {
            bf16x8 a = *(const bf16x8*)(Abase + ks*32);
            #pragma unroll
            for (int ct = 0; ct < 18; ++ct) {
                const int seg = ct / 6, u = ct % 6;
                const int gcol = seg*192 + g*96 + u*16;
                bf16x8 b = *(const bf16x8*)(Wqb + (size_t)(gcol + fr)*192 + ks*32 + fg*8);
                acc[ct] = __builtin_amdgcn_mfma_f32_16x16x32_bf16(a, b, acc[ct], 0, 0, 0);
            }
        }
        // ---- epilogue -> LDS (Q/K [n][d], V transposed [d][n]) ----
        #pragma unroll
        for (int ct = 0; ct < 18; ++ct) {
            const int seg = ct / 6, u = ct % 6;
            const int hl = u >> 1, dp = u & 1;
            if (seg < 2) {
                #pragma unroll
                for (int e = 0; e < 4; ++e)
                    QK[seg][hl][trow + fg*4 + e][dp*16 + fr] = f2bf(acc[ct][e]);
            } else {
                ushort4 v4;
                v4.x = f2bf(acc[ct][0]); v4.y = f2bf(acc[ct][1]);
                v4.z = f2bf(acc[ct][2]); v4.w = f2bf(acc[ct][3]);
                *reinterpret_cast<ushort4*>(&Vt[hl][dp*16 + fr][trow + fg*4]) = v4;
            }
        }
        __syncthreads();
        // ---- normalize Q (fold logit scale) and K rows, fp32 ----
        {
            float scq[3];
            #pragma unroll
            for (int hl = 0; hl < 3; ++hl)
                scq[hl] = expf(fminf(ls[g*3 + hl], 4.6051701859880914f));
            for (int rr = t; rr < 384; rr += 256) {
                const int mat = rr / 192, rem = rr - mat*192;
                const int hl = rem >> 6, n = rem & 63;
                ushort* p = &QK[mat][hl][n][0];
                float vals[32];
                float ss = 0.f;
                #pragma unroll
                for (int j = 0; j < 8; ++j) {
                    ushort4 u4 = *reinterpret_cast<const ushort4*>(p + j*4);
                    float a0 = bf2f(u4.x), a1 = bf2f(u4.y), a2 = bf2f(u4.z), a3 = bf2f(u4.w);
                    vals[j*4+0]=a0; vals[j*4+1]=a1; vals[j*4+2]=a2; vals[j*4+3]=a3;
                    ss += a0*a0 + a1*a1 + a2*a2 + a3*a3;
                }
                float f = 1.f / fmaxf(sqrtf(ss), 1e-12f);
                if (mat == 0) f *= (hl == 0 ? scq[0] : (hl == 1 ? scq[1] : scq[2]));
                #pragma unroll
                for (int j = 0; j < 8; ++j) {
                    ushort4 o;
                    o.x = f2bf(vals[j*4+0]*f); o.y = f2bf(vals[j*4+1]*f);
                    o.z = f2bf(vals[j*4+2]*f); o.w = f2bf(vals[j*4+3]*f);
                    *reinterpret_cast<ushort4*>(p + j*4) = o;
                }
            }
        }
        __syncthreads();
        // ---- per-head attention; wave-private rows [trow, trow+16) ----
        #pragma unroll 1
        for (int hl = 0; hl < 3; ++hl) {
            const int h = g*3 + hl;
            bf16x8 qf = *(const bf16x8*)&QK[0][hl][trow + fr][fg*8];
            f32x4 accS[4] = {};
            #pragma unroll
            for (int j = 0; j < 4; ++j) {
                bf16x8 kf = *(const bf16x8*)&QK[1][hl][j*16 + fr][fg*8];
                accS[j] = __builtin_amdgcn_mfma_f32_16x16x32_bf16(qf, kf, accS[j], 0, 0, 0);
            }
            float s[4][4];
            const float* bi = bias16 + h*4096;
            const float* mk = amask + (size_t)win*4096;
            #pragma unroll
            for (int e = 0; e < 4; ++e) {
                const int r = trow + fg*4 + e;
                #pragma unroll
                for (int j = 0; j < 4; ++j) {
                    const int c = j*16 + fr;
                    s[j][e] = accS[j][e] + bi[r*64 + c] + mk[r*64 + c];
                }
            }
            #pragma unroll
            for (int e = 0; e < 4; ++e) {
                float m0 = fmaxf(fmaxf(s[0][e], s[1][e]), fmaxf(s[2][e], s[3][e]));
                m0 = fmaxf(m0, __shfl_xor(m0, 1));
                m0 = fmaxf(m0, __shfl_xor(m0, 2));
                m0 = fmaxf(m0, __shfl_xor(m0, 4));
                m0 = fmaxf(m0, __shfl_xor(m0, 8));
                float s0 = 0.f;
                #pragma unroll
                for (int j = 0; j < 4; ++j) { s[j][e] = expf(s[j][e] - m0); s0 += s[j][e]; }
                s0 += __shfl_xor(s0, 1);
                s0 += __shfl_xor(s0, 2);
                s0 += __shfl_xor(s0, 4);
                s0 += __shfl_xor(s0, 8);
                const float rs = 1.f / s0;
                #pragma unroll
                for (int j = 0; j < 4; ++j)
                    Pl[wid][fg*4 + e][j*16 + fr] = f2bf(s[j][e] * rs);
            }
            f32x4 accO[2] = {};
            #pragma unroll
            for (int kk = 0; kk < 2; ++kk) {
                bf16x8 pa = *(const bf16x8*)&Pl[wid][fr][kk*32 + fg*8];
                #pragma unroll
                for (int j = 0; j < 2; ++j) {
                    bf16x8 vb = *(const bf16x8*)&Vt[hl][j*16 + fr][kk*32 + fg*8];
                    accO[j] = __builtin_amdgcn_mfma_f32_16x16x32_bf16(pa, vb, accO[j], 0, 0, 0);
                }
            }
            #pragma unroll
            for (int j = 0; j < 2; ++j) {
                #pragma unroll
                for (int e = 0; e < 4; ++e) {
                    buf2[(size_t)wb*12288 + (size_t)(trow + fg*4 + e)*192 + h*32 + j*16 + fr]
                        = f2bf(accO[j][e]);
                }
            }
        }
    }
}

// ---------------- K3: proj (MFMA bf16) + window reverse + roll(+2) + residual ----------------
__global__ __launch_bounds__(256) void k_proj(
        const ushort* __restrict__ buf2, const float* __restrict__ x,
        const ushort* __restrict__ Wpb, const float* __restrict__ pb,
        float* __restrict__ out) {
    __shared__ ushort As[64 * 200];
    __shared__ int rowbase[64];
    const int t = threadIdx.x;
    const size_t base = (size_t)blockIdx.x * 64;
    if (t < 64) {
        int dst = (int)base + t;
        int b = dst / 13824, r1 = dst - b * 13824;
        int d = r1 / 576, h2 = (r1 / 24) % 24, w2 = r1 % 24;
        int dd = (d + 22) % 24, hh = (h2 + 22) % 24, ww = (w2 + 22) % 24;
        int win = ((dd >> 2)*6 + (hh >> 2))*6 + (ww >> 2);
        int n = ((dd & 3) << 4) | ((hh & 3) << 2) | (ww & 3);
        rowbase[t] = ((b*216 + win)*64 + n) * 192;
    }
    __syncthreads();
    {
        const int r = t >> 2, q = t & 3;
        const ushort* src = buf2 + rowbase[r] + q*48;
        #pragma unroll
        for (int i = 0; i < 6; ++i)
            *(bf16x8*)(As + r*200 + q*48 + i*8) = *(const bf16x8*)(src + i*8);
    }
    __syncthreads();

    const int wid = t >> 6, lane = t & 63;
    const int fr = lane & 15, fg = lane >> 4;
    const int trow = wid * 16;
    f32x4 acc[12] = {};
    #pragma unroll
    for (int ks = 0; ks < 6; ++ks) {
        bf16x8 a = *(const bf16x8*)(As + (trow + fr)*200 + ks*32 + fg*8);
        #pragma unroll
        for (int j = 0; j < 12; ++j) {
            bf16x8 b = *(const bf16x8*)(Wpb + (size_t)(j*16 + fr)*192 + ks*32 + fg*8);
            acc[j] = __builtin_amdgcn_mfma_f32_16x16x32_bf16(a, b, acc[j], 0, 0, 0);
        }
    }
    #pragma unroll
    for (int j = 0; j < 12; ++j) {
        int c = j*16 + fr;
        float bias = pb[c];
        #pragma unroll
        for (int e = 0; e < 4; ++e) {
            size_t idx = (base + trow + fg*4 + e)*192 + c;
            out[idx] = x[idx] + acc[j][e] + bias;
        }
    }
}

// ---------------- K4: fused LN2 + FC1 + GELU + FC2 + residual (barrier-free) ----------------
// 864 blocks x 128 tokens; 4 waves x 32 tokens each, fully wave-private.
// A (LN2'd) register-resident; hidden chunk = 64 (W chunks L1-resident);
// every B-fragment load feeds 2 MFMAs.
__global__ __launch_bounds__(256, 2) void k_mlp3(
        const ushort* __restrict__ W1b, const ushort* __restrict__ W2b,
        const float* __restrict__ n2w, const float* __restrict__ n2b,
        const float* __restrict__ f1b, const float* __restrict__ f2b,
        float* __restrict__ out) {
    __shared__ ushort As[4][32][200];
    __shared__ ushort Hs[4][32][68];
    const int t = threadIdx.x;
    const int wid = t >> 6, lane = t & 63;
    const size_t tok0 = (size_t)blockIdx.x * 128 + wid * 32;  // wave-owned 32 tokens

    // ---- LN2 of the wave's 32 tokens -> As[wid] (bf16); 2 lanes/token ----
    {
        const int r = lane >> 1, half = lane & 1;
        const float* hp = out + (tok0 + r) * 192 + half * 96;
        float4 v[24];
        float sum = 0.f, ssum = 0.f;
        #pragma unroll
        for (int j = 0; j < 24; ++j) {
            v[j] = reinterpret_cast<const float4*>(hp)[j];
            sum  += v[j].x + v[j].y + v[j].z + v[j].w;
            ssum += v[j].x*v[j].x + v[j].y*v[j].y + v[j].z*v[j].z + v[j].w*v[j].w;
        }
        sum  += __shfl_xor(sum, 1);
        ssum += __shfl_xor(ssum, 1);
        float mu = sum * (1.f/192.f);
        float inv = rsqrtf(ssum * (1.f/192.f) - mu*mu + 1e-5f);
        #pragma unroll
        for (int j = 0; j < 24; ++j) {
            int c = half*96 + j*4;
            ushort4 o;
            o.x = f2bf((v[j].x - mu)*inv*n2w[c+0] + n2b[c+0]);
            o.y = f2bf((v[j].y - mu)*inv*n2w[c+1] + n2b[c+1]);
            o.z = f2bf((v[j].z - mu)*inv*n2w[c+2] + n2b[c+2]);
            o.w = f2bf((v[j].w - mu)*inv*n2w[c+3] + n2b[c+3]);
            *reinterpret_cast<ushort4*>(&As[wid][r][c]) = o;
        }
    }
    // wave-private LDS: no __syncthreads needed anywhere.

    const int fr = lane & 15, fg = lane >> 4;
    // ---- A fragments -> registers (32 tok x 192 ch) ----
    bf16x8 a[2][6];
    #pragma unroll
    for (int tf = 0; tf < 2; ++tf)
        #pragma unroll
        for (int ks = 0; ks < 6; ++ks)
            a[tf][ks] = *(const bf16x8*)&As[wid][tf*16 + fr][ks*32 + fg*8];

    f32x4 acc2[2][12] = {};

    for (int hb = 0; hb < 768; hb += 64) {
        // ---- FC1: 32 tok x 64 hidden ----
        f32x4 acc1[2][4] = {};
        #pragma unroll
        for (int ks = 0; ks < 6; ++ks) {
            bf16x8 b[4];
            #pragma unroll
            for (int j = 0; j < 4; ++j)
                b[j] = *(const bf16x8*)(W1b + (size_t)(hb + j*16 + fr)*192 + ks*32 + fg*8);
            #pragma unroll
            for (int j = 0; j < 4; ++j) {
                acc1[0][j] = __builtin_amdgcn_mfma_f32_16x16x32_bf16(a[0][ks], b[j], acc1[0][j], 0, 0, 0);
                acc1[1][j] = __builtin_amdgcn_mfma_f32_16x16x32_bf16(a[1][ks], b[j], acc1[1][j], 0, 0, 0);
            }
        }
        // ---- bias + GELU -> Hs (wave-private) ----
        #pragma unroll
        for (int j = 0; j < 4; ++j) {
            float bias = f1b[hb + j*16 + fr];
            #pragma unroll
            for (int tf = 0; tf < 2; ++tf) {
                #pragma unroll
                for (int e = 0; e < 4; ++e) {
                    float h = acc1[tf][j][e] + bias;
                    h = 0.5f*h*(1.f + erff(h*0.70710678118654752f));
                    Hs[wid][tf*16 + fg*4 + e][j*16 + fr] = f2bf(h);
                }
            }
        }
        // ---- FC2 partial over this hidden chunk ----
        #pragma unroll
        for (int ks2 = 0; ks2 < 2; ++ks2) {
            bf16x8 ha0 = *(const bf16x8*)&Hs[wid][fr][ks2*32 + fg*8];
            bf16x8 ha1 = *(const bf16x8*)&Hs[wid][16 + fr][ks2*32 + fg*8];
            #pragma unroll
            for (int j = 0; j < 12; ++j) {
                bf16x8 b = *(const bf16x8*)(W2b + (size_t)(j*16 + fr)*768 + hb + ks2*32 + fg*8);
                acc2[0][j] = __builtin_amdgcn_mfma_f32_16x16x32_bf16(ha0, b, acc2[0][j], 0, 0, 0);
                acc2[1][j] = __builtin_amdgcn_mfma_f32_16x16x32_bf16(ha1, b, acc2[1][j], 0, 0, 0);
            }
        }
    }

    // ---- epilogue: out += mlp + f2b ----
    #pragma unroll
    for (int j = 0; j < 12; ++j) {
        int c = j*16 + fr;
        float bias = f2b[c];
        #pragma unroll
        for (int tf = 0; tf < 2; ++tf) {
            #pragma unroll
            for (int e = 0; e < 4; ++e) {
                size_t idx = (tok0 + tf*16 + fg*4 + e)*192 + c;
                out[idx] += acc2[tf][j][e] + bias;
            }
        }
    }
}

extern "C" void kernel_launch(void* const* d_in, const int* in_sizes, int n_in,
                              void* d_out, int out_size, void* d_ws, size_t ws_size,
                              hipStream_t stream) {
    const float* x     = (const float*)d_in[0];
    const float* n1w   = (const float*)d_in[1];
    const float* n1b   = (const float*)d_in[2];
    const float* qkvw  = (const float*)d_in[3];
    const float* ls    = (const float*)d_in[6];
    const float* cpw1  = (const float*)d_in[7];
    const float* cpb1  = (const float*)d_in[8];
    const float* cpw2  = (const float*)d_in[9];
    const float* pw    = (const float*)d_in[10];
    const float* pb    = (const float*)d_in[11];
    const float* n2w   = (const float*)d_in[12];
    const float* n2b   = (const float*)d_in[13];
    const float* f1w   = (const float*)d_in[14];
    const float* f1b   = (const float*)d_in[15];
    const float* f2w   = (const float*)d_in[16];
    const float* f2b   = (const float*)d_in[17];
    const float* rtab  = (const float*)d_in[18];
    const int*   ridx  = (const int*)d_in[19];
    const float* amask = (const float*)d_in[20];
    float* out = (float*)d_out;

    // ws layout (all bf16/ushort unless noted); total ~86 MB
    ushort* buf1 = (ushort*)d_ws;          // 21233664 (LN1'd x, [win][n][c])
    ushort* buf2 = buf1 + 21233664;        // 21233664 (attn out, [win][n][c])
    ushort* Wqb  = buf2 + 21233664;        // 110592
    ushort* W1b  = Wqb + 110592;           // 147456
    ushort* W2b  = W1b + 147456;           // 147456
    ushort* Wpb  = W2b + 147456;           // 36864
    float*  tblo = (float*)(Wpb + 36864);  // 2058 (+pad)
    float*  b16  = tblo + 2064;            // 24576

    k_cpb_table<<<dim3(9),    dim3(256), 0, stream>>>(rtab, cpw1, cpb1, cpw2, tblo);
    k_bias16   <<<dim3(96),   dim3(256), 0, stream>>>(tblo, ridx, b16);
    k_wcvt     <<<dim3(576),  dim3(256), 0, stream>>>(qkvw, f1w, f2w, pw, Wqb, W1b, W2b, Wpb);
    k_ln1      <<<dim3(1728), dim3(256), 0, stream>>>(x, n1w, n1b, buf1);
    k_attn3    <<<dim3(1728), dim3(256), 0, stream>>>(buf1, Wqb, ls, b16, amask, buf2);
    k_proj     <<<dim3(1728), dim3(256), 0, stream>>>(buf2, x, Wpb, pb, out);
    k_mlp3     <<<dim3(864),  dim3(256), 0, stream>>>(W1b, W2b, n2w, n2b, f1b, f2b, out);
}